// Round 18
// baseline (647.087 us; speedup 1.0000x reference)
//
#include <hip/hip_runtime.h>

#define NPTS 40000
#define NEDGE 1000000
#define BN_EPS 1e-5f

typedef short bf16x8 __attribute__((ext_vector_type(8)));
typedef float f32x4 __attribute__((ext_vector_type(4)));

__device__ __forceinline__ unsigned short f2bf(float x) {
    unsigned u = __float_as_uint(x);
    return (unsigned short)((u + 0x7FFFu + ((u >> 16) & 1u)) >> 16);  // RTN-even
}
__device__ __forceinline__ float rfl_f(float x) {
    return __uint_as_float(__builtin_amdgcn_readfirstlane(__float_as_uint(x)));
}

// ===========================================================================
// Edge geometry: validity + cell + PRE-MULTIPLIED corner weights
// (w00,w01,w10,w11) = win * ((1-fx),fx) x ((1-fy),fy). Corner (dx,dy) maps
// to cell + dx*4 + dy.
// ===========================================================================
__device__ inline bool edge_geom(const float* rel_pos, const int* ws_ptr, int e,
                                 int& cell, float4& w4) {
    float ws = (float)ws_ptr[0];
    float inv_ws = 1.0f / ws;
    float ux = rel_pos[2 * e] * inv_ws;
    float uy = rel_pos[2 * e + 1] * inv_ws;
    float q = 1.0f - (ux * ux + uy * uy);
    if (!(q > 0.0f)) return false;
    float win = q * q * q;
    float gx = fminf(fmaxf((ux + 1.0f) * 1.5f, 0.0f), 3.0f);
    float gy = fminf(fmaxf((uy + 1.0f) * 1.5f, 0.0f), 3.0f);
    int ix = (int)floorf(gx); ix = ix < 0 ? 0 : (ix > 2 ? 2 : ix);
    int iy = (int)floorf(gy); iy = iy < 0 ? 0 : (iy > 2 ? 2 : iy);
    float fx = gx - (float)ix;
    float fy = gy - (float)iy;
    cell = ix * 4 + iy;
    float wx0 = (1.f - fx) * win, wx1 = fx * win;
    float wy0 = 1.f - fy, wy1 = fy;
    w4 = make_float4(wx0 * wy0, wx0 * wy1, wx1 * wy0, wx1 * wy1);
    return true;
}

__global__ void hist_kernel(const float* __restrict__ rel_pos,
                            const int* __restrict__ receivers,
                            const int* __restrict__ ws_ptr,
                            int* __restrict__ cnt) {
    int e = blockIdx.x * blockDim.x + threadIdx.x;
    if (e >= NEDGE) return;
    int cell; float4 w4;
    if (edge_geom(rel_pos, ws_ptr, e, cell, w4))
        atomicAdd(&cnt[receivers[e]], 1);
}

// one block, 1024 threads: exclusive scan of 40000 counts -> rowptr[40001]
__global__ __launch_bounds__(1024) void scan_kernel(const int* __restrict__ cnt,
                                                    int* __restrict__ rowptr) {
    __shared__ int part[1024];
    int t = threadIdx.x;
    const int CHUNK = 40;
    int base = t * CHUNK;
    int s = 0;
    if (t < 1000)
        for (int i = 0; i < CHUNK; ++i) s += cnt[base + i];
    part[t] = s;
    __syncthreads();
    for (int off = 1; off < 1024; off <<= 1) {
        int v = (t >= off) ? part[t - off] : 0;
        __syncthreads();
        part[t] += v;
        __syncthreads();
    }
    int excl = (t == 0) ? 0 : part[t - 1];
    if (t < 1000) {
        int run = excl;
        for (int i = 0; i < CHUNK; ++i) { rowptr[base + i] = run; run += cnt[base + i]; }
        if (t == 999) rowptr[NPTS] = run;
    }
}

__global__ void fill_kernel(const float* __restrict__ rel_pos,
                            const int* __restrict__ receivers,
                            const int* __restrict__ senders,
                            const int* __restrict__ ws_ptr,
                            const int* __restrict__ rowptr,
                            int* __restrict__ cursor,
                            int2* __restrict__ sc,
                            float4* __restrict__ ew4) {
    int e = blockIdx.x * blockDim.x + threadIdx.x;
    if (e >= NEDGE) return;
    int cell; float4 w4;
    if (!edge_geom(rel_pos, ws_ptr, e, cell, w4)) return;
    int recv = receivers[e];
    int pos = rowptr[recv] + atomicAdd(&cursor[recv], 1);
    sc[pos] = make_int2(senders[e], cell);
    ew4[pos] = w4;
}

// ===========================================================================
// Merged W repack into bf16 MFMA B-fragment layout:
// Wp[((cb*nKS+ks)*64+l)*8+j] = bf16(W[ks*32+(l>>4)*8+j][cb*16+(l&15)])
// ===========================================================================
__global__ void pack_all_kernel(const float* __restrict__ W1, const float* __restrict__ W2,
                                const float* __restrict__ W3, const float* __restrict__ W4,
                                unsigned short* __restrict__ Wp1, unsigned short* __restrict__ Wp2,
                                unsigned short* __restrict__ Wp3, unsigned short* __restrict__ Wp4) {
    int idx = blockIdx.x * 256 + threadIdx.x;
    const float* W; unsigned short* Wp; int M, COUT, base;
    if (idx < 65536)       { W = W1; Wp = Wp1; M = 1024; COUT = 64; base = 0; }
    else if (idx < 98304)  { W = W2; Wp = Wp2; M = 1024; COUT = 32; base = 65536; }
    else if (idx < 131072) { W = W3; Wp = Wp3; M = 512;  COUT = 64; base = 98304; }
    else if (idx < 163840) { W = W4; Wp = Wp4; M = 1024; COUT = 32; base = 131072; }
    else return;
    int i = idx - base;
    int nKS = M / 32;
    int j = i & 7, l = (i >> 3) & 63, t = i >> 9;
    int ks = t % nKS, cb = t / nKS;
    int m = ks * 32 + (l >> 4) * 8 + j;
    int col = cb * 16 + (l & 15);
    Wp[i] = f2bf(W[(size_t)m * COUT + col]);
}

// ===========================================================================
// Fused cconv layer: 1024 threads = 16 waves = 16 receivers (1 wave each).
// Phase 1: all 64 lanes of a wave process the SAME edge (lane = channel);
// cell + 4 corner weights readfirstlane'd -> wave-uniform switch does exactly
// 4 fma into static acc[16] (vs 64 fma + masking in the slot layout), loop
// runs deg (not max-of-4). Phase 2: MFMA, wave (cb,kq) = colblock x K-quarter,
// partials pair-reduced in LDS. BN partial stats fused in epilogue.
// MODE 0: feat [N][CIN];  MODE 1: concat(x,y) gather (layer 1).
// ===========================================================================
template <int CIN, int COUT, int MODE>
__global__ __launch_bounds__(1024, 4) void fused_layer(const float* __restrict__ feat,
                                                       const float* __restrict__ xin,
                                                       const float* __restrict__ yin,
                                                       const int2* __restrict__ sc,
                                                       const float4* __restrict__ ew4,
                                                       const int* __restrict__ rowptr,
                                                       const unsigned short* __restrict__ Wp,
                                                       const float* __restrict__ a,
                                                       float* __restrict__ P,
                                                       float* __restrict__ part) {
    constexpr int RB = 16;            // receivers per block (= waves)
    constexpr int M = 16 * CIN;       // GEMM K dimension
    constexpr int LDB = M + 8;        // bf16 row stride (pad 8)
    constexpr int nKS = M / 32;       // MFMA K-steps
    constexpr int CT = COUT / 16;     // colblocks (4 or 2)
    constexpr int NKQ = 16 / CT;      // K-quarter waves per colblock
    constexpr int KS_PER = nKS / NKQ; // MFMA K-steps per wave
    __shared__ short S_bf[RB * LDB];
    __shared__ float Rred[(NKQ - 1) * CT * 256];

    int tid = threadIdx.x;
    int lane = tid & 63;
    int wave = tid >> 6;              // 0..15 = receiver
    int ch = (CIN == 64) ? lane : (lane & 31);
    int rglob = blockIdx.x * RB + wave;
    int rs = __builtin_amdgcn_readfirstlane(rowptr[rglob]);
    int deg = __builtin_amdgcn_readfirstlane(rowptr[rglob + 1]) - rs;

    // feat base: per-lane channel pointer
    const float* fbase;
    int fstride;
    if constexpr (MODE == 1) {
        fbase = (ch < 32) ? (xin + ch) : (yin + (ch - 32));
        fstride = 32;
    } else {
        fbase = feat + ch;
        fstride = CIN;
    }

    float acc[16];
#pragma unroll
    for (int cc = 0; cc < 16; ++cc) acc[cc] = 0.f;

#define CC_CASE(c)                                                            \
    case c:                                                                   \
        acc[c] = fmaf(w00, f, acc[c]);                                        \
        acc[c + 1] = fmaf(w01, f, acc[c + 1]);                                \
        acc[c + 4] = fmaf(w10, f, acc[c + 4]);                                \
        acc[c + 5] = fmaf(w11, f, acc[c + 5]);                                \
        break;

#pragma unroll 2
    for (int k = 0; k < deg; ++k) {
        int e = rs + k;
        int2 rec = sc[e];
        float4 w = ew4[e];
        int sender = __builtin_amdgcn_readfirstlane(rec.x);
        int cell = __builtin_amdgcn_readfirstlane(rec.y);
        float w00 = rfl_f(w.x), w01 = rfl_f(w.y), w10 = rfl_f(w.z), w11 = rfl_f(w.w);
        float f = fbase[(size_t)sender * fstride];
        switch (cell) {
            CC_CASE(0) CC_CASE(1) CC_CASE(2)
            CC_CASE(4) CC_CASE(5) CC_CASE(6)
            CC_CASE(8) CC_CASE(9) CC_CASE(10)
            default: break;
        }
    }
#undef CC_CASE

    // --- handoff: acc[16] -> bf16 LDS row (lane ch of each cell) ---
    {
        short* srow = &S_bf[wave * LDB];
        if (CIN == 64 || lane < 32) {
#pragma unroll
            for (int cc = 0; cc < 16; ++cc)
                srow[cc * CIN + ch] = (short)f2bf(acc[cc]);
        }
    }
    __syncthreads();

    // --- phase 2: MFMA GEMM, wave = (cb, kq) ---
    int row16 = lane & 15;
    int kgrp = lane >> 4;
    int cb = wave % CT;
    int kq = wave / CT;
    int ks0 = kq * KS_PER;
    f32x4 c = {0.f, 0.f, 0.f, 0.f};

    const short* abase = &S_bf[row16 * LDB + kgrp * 8];
    const bf16x8* wfrag = (const bf16x8*)Wp;
    size_t wbase = (size_t)(cb * nKS + ks0) * 64 + lane;
#pragma unroll
    for (int kk = 0; kk < KS_PER; ++kk) {
        bf16x8 af = *(const bf16x8*)(abase + (size_t)(ks0 + kk) * 32);
        bf16x8 bf = wfrag[wbase + (size_t)kk * 64];
        c = __builtin_amdgcn_mfma_f32_16x16x32_bf16(af, bf, c, 0, 0, 0);
    }

    if (kq > 0) {
        float* r = &Rred[((cb * (NKQ - 1)) + (kq - 1)) * 256];
#pragma unroll
        for (int i = 0; i < 4; ++i)
            r[(kgrp * 4 + i) * 16 + row16] = c[i];
    }
    __syncthreads();
    if (kq == 0) {
        float sp = 0.f, sq = 0.f;
#pragma unroll
        for (int i = 0; i < 4; ++i) {
            int row = kgrp * 4 + i;
            float v = c[i];
#pragma unroll
            for (int p2 = 0; p2 < NKQ - 1; ++p2)
                v += Rred[((cb * (NKQ - 1)) + p2) * 256 + row * 16 + row16];
            int n = blockIdx.x * RB + row;
            v *= a[n];
            P[(size_t)n * COUT + cb * 16 + row16] = v;
            sp += v; sq += v * v;
        }
        sp += __shfl_xor(sp, 16); sp += __shfl_xor(sp, 32);
        sq += __shfl_xor(sq, 16); sq += __shfl_xor(sq, 32);
        if (kgrp == 0) {
            part[(size_t)blockIdx.x * 2 * COUT + cb * 16 + row16] = sp;
            part[(size_t)blockIdx.x * 2 * COUT + COUT + cb * 16 + row16] = sq;
        }
    }
}

// ===========================================================================
// BN finalize: reduce 2500 per-block partials -> scale/shift.
// ===========================================================================
template <int COUT>
__global__ __launch_bounds__(256) void finalize_bn_kernel(const float* __restrict__ part,
                                                          const float* __restrict__ g,
                                                          const float* __restrict__ b,
                                                          float* __restrict__ scb) {
    constexpr int C2 = 2 * COUT;
    constexpr int NG = 256 / C2;
    constexpr int NB = NPTS / 16;
    constexpr int PER = NB / NG;
    __shared__ float ls[256];
    int tid = threadIdx.x;
    int d = tid % C2;
    int gi = tid / C2;
    float s = 0.f;
    int k0 = gi * PER;
    for (int k = k0; k < k0 + PER; ++k) s += part[(size_t)k * C2 + d];
    ls[tid] = s;
    __syncthreads();
    float tot = 0.f;
    if (tid < C2) {
        tot = ls[tid];
        for (int g2 = 1; g2 < NG; ++g2) tot += ls[tid + g2 * C2];
    }
    __syncthreads();
    if (tid < C2) ls[tid] = tot;
    __syncthreads();
    if (tid < COUT) {
        float sum = ls[tid], ssq = ls[COUT + tid];
        float mean = sum / (float)NPTS;
        float var = ssq / (float)NPTS - mean * mean;
        float inv = rsqrtf(var + BN_EPS);
        float scale = inv * g[tid];
        scb[tid] = scale;
        scb[COUT + tid] = b[tid] - mean * scale;
    }
}

template <int COUT>
__global__ void apply_relu_kernel(float* __restrict__ P, const float* __restrict__ scb) {
    int t = blockIdx.x * blockDim.x + threadIdx.x;
    if (t >= NPTS * COUT) return;
    int d = t % COUT;
    float v = P[t] * scb[d] + scb[COUT + d];
    P[t] = fmaxf(v, 0.0f);
}

__global__ void apply_sigmix_kernel(const float* __restrict__ P,
                                    const float* __restrict__ scb,
                                    const float* __restrict__ x,
                                    const float* __restrict__ y,
                                    float* __restrict__ out) {
    int t = blockIdx.x * blockDim.x + threadIdx.x;
    if (t >= NPTS * 32) return;
    int d = t & 31;
    float v = P[t] * scb[d] + scb[32 + d];
    float w = 1.0f / (1.0f + expf(-v));
    out[t] = 2.0f * x[t] * w + 2.0f * y[t] * (1.0f - w);
}

extern "C" void kernel_launch(void* const* d_in, const int* in_sizes, int n_in,
                              void* d_out, int out_size, void* d_ws, size_t ws_size,
                              hipStream_t stream) {
    const float* x = (const float*)d_in[0];
    const float* y = (const float*)d_in[1];
    const int* senders = (const int*)d_in[2];
    const int* receivers = (const int*)d_in[3];
    const float* rel_pos = (const float*)d_in[4];
    const int* ws_ptr = (const int*)d_in[5];
    const float* a = (const float*)d_in[6];
    const float* W1 = (const float*)d_in[7];
    const float* W2 = (const float*)d_in[8];
    const float* W3 = (const float*)d_in[9];
    const float* W4 = (const float*)d_in[10];
    const float* g1 = (const float*)d_in[11];
    const float* b1 = (const float*)d_in[12];
    const float* g2 = (const float*)d_in[13];
    const float* b2 = (const float*)d_in[14];
    const float* g3 = (const float*)d_in[15];
    const float* b3 = (const float*)d_in[16];
    const float* g4 = (const float*)d_in[17];
    const float* b4 = (const float*)d_in[18];

    char* ws = (char*)d_ws;
    size_t off = 0;
    auto alloc = [&](size_t bytes) -> void* {
        void* p = ws + off;
        off += (bytes + 255) & ~(size_t)255;
        return p;
    };
    int* cnt = (int*)alloc((size_t)NPTS * sizeof(int));      // contiguous with
    int* cursor = (int*)alloc((size_t)NPTS * sizeof(int));   // cursor: 1 memset
    int* rowptr = (int*)alloc((size_t)(NPTS + 1) * sizeof(int));
    int2* sc = (int2*)alloc((size_t)(NEDGE + 4) * sizeof(int2));
    float4* ew4 = (float4*)alloc((size_t)(NEDGE + 4) * sizeof(float4));
    float* xa = (float*)alloc((size_t)NPTS * 64 * sizeof(float));  // P3
    float* P1 = (float*)alloc((size_t)NPTS * 64 * sizeof(float));
    float* P2 = (float*)alloc((size_t)NPTS * 32 * sizeof(float));  // also P4
    float* xo = (float*)alloc((size_t)NPTS * 32 * sizeof(float));
    float* part = (float*)alloc((size_t)(NPTS / 16) * 128 * sizeof(float));
    float* scb = (float*)alloc(2 * 64 * sizeof(float));
    unsigned short* Wp1 = (unsigned short*)alloc((size_t)1024 * 64 * 2);
    unsigned short* Wp2 = (unsigned short*)alloc((size_t)1024 * 32 * 2);
    unsigned short* Wp3 = (unsigned short*)alloc((size_t)512 * 64 * 2);
    unsigned short* Wp4 = (unsigned short*)alloc((size_t)1024 * 32 * 2);
    (void)ws_size; (void)in_sizes; (void)n_in; (void)out_size;

    // --- prologue: packs (1 launch), CSR build, single memset ---
    pack_all_kernel<<<640, 256, 0, stream>>>(W1, W2, W3, W4, Wp1, Wp2, Wp3, Wp4);
    hipMemsetAsync(cnt, 0, (size_t)2 * NPTS * sizeof(int), stream);  // cnt+cursor
    hist_kernel<<<(NEDGE + 255) / 256, 256, 0, stream>>>(rel_pos, receivers, ws_ptr, cnt);
    scan_kernel<<<1, 1024, 0, stream>>>(cnt, rowptr);
    fill_kernel<<<(NEDGE + 255) / 256, 256, 0, stream>>>(rel_pos, receivers, senders, ws_ptr,
                                                         rowptr, cursor, sc, ew4);

    // Layer 1: cconv(concat(x,y); W1) -> P1 (+stats), relu(bn) in place
    fused_layer<64, 64, 1><<<NPTS / 16, 1024, 0, stream>>>(nullptr, x, y, sc, ew4, rowptr,
                                                           Wp1, a, P1, part);
    finalize_bn_kernel<64><<<1, 256, 0, stream>>>(part, g1, b1, scb);
    apply_relu_kernel<64><<<(NPTS * 64 + 255) / 256, 256, 0, stream>>>(P1, scb);

    // Layer 2: cconv(P1; W2) -> P2 (+stats), sigmoid-mix -> xo
    fused_layer<64, 32, 0><<<NPTS / 16, 1024, 0, stream>>>(P1, nullptr, nullptr, sc, ew4, rowptr,
                                                           Wp2, a, P2, part);
    finalize_bn_kernel<32><<<1, 256, 0, stream>>>(part, g2, b2, scb);
    apply_sigmix_kernel<<<(NPTS * 32 + 255) / 256, 256, 0, stream>>>(P2, scb, x, y, xo);

    // Layer 3: cconv(xo; W3) -> xa (+stats), relu(bn) in place
    fused_layer<32, 64, 0><<<NPTS / 16, 1024, 0, stream>>>(xo, nullptr, nullptr, sc, ew4, rowptr,
                                                           Wp3, a, xa, part);
    finalize_bn_kernel<64><<<1, 256, 0, stream>>>(part, g3, b3, scb);
    apply_relu_kernel<64><<<(NPTS * 64 + 255) / 256, 256, 0, stream>>>(xa, scb);

    // Layer 4: cconv(xa; W4) -> P2 (+stats), sigmoid-mix -> out
    fused_layer<64, 32, 0><<<NPTS / 16, 1024, 0, stream>>>(xa, nullptr, nullptr, sc, ew4, rowptr,
                                                           Wp4, a, P2, part);
    finalize_bn_kernel<32><<<1, 256, 0, stream>>>(part, g4, b4, scb);
    apply_sigmix_kernel<<<(NPTS * 32 + 255) / 256, 256, 0, stream>>>(P2, scb, x, y, (float*)d_out);
}

// Round 19
// 627.208 us; speedup vs baseline: 1.0317x; 1.0317x over previous
//
#include <hip/hip_runtime.h>

#define NPTS 40000
#define NEDGE 1000000
#define BN_EPS 1e-5f

typedef short bf16x8 __attribute__((ext_vector_type(8)));
typedef float f32x4 __attribute__((ext_vector_type(4)));

__device__ __forceinline__ unsigned short f2bf(float x) {
    unsigned u = __float_as_uint(x);
    return (unsigned short)((u + 0x7FFFu + ((u >> 16) & 1u)) >> 16);  // RTN-even
}
__device__ __forceinline__ float bflo(unsigned x) { return __uint_as_float(x << 16); }
__device__ __forceinline__ float bfhi(unsigned x) { return __uint_as_float(x & 0xFFFF0000u); }

// ===========================================================================
// Edge geometry: validity + cell + factorized weights.
// w4 = (wx0*win, wx1*win, fy, 0); per-cell weight = wxv(cx)*wyv(cy).
// ===========================================================================
__device__ inline bool edge_geom(const float* rel_pos, const int* ws_ptr, int e,
                                 int& cell, float4& w4) {
    float ws = (float)ws_ptr[0];
    float inv_ws = 1.0f / ws;
    float ux = rel_pos[2 * e] * inv_ws;
    float uy = rel_pos[2 * e + 1] * inv_ws;
    float q = 1.0f - (ux * ux + uy * uy);
    if (!(q > 0.0f)) return false;
    float win = q * q * q;
    float gx = fminf(fmaxf((ux + 1.0f) * 1.5f, 0.0f), 3.0f);
    float gy = fminf(fmaxf((uy + 1.0f) * 1.5f, 0.0f), 3.0f);
    int ix = (int)floorf(gx); ix = ix < 0 ? 0 : (ix > 2 ? 2 : ix);
    int iy = (int)floorf(gy); iy = iy < 0 ? 0 : (iy > 2 ? 2 : iy);
    float fx = gx - (float)ix;
    float fy = gy - (float)iy;
    cell = ix * 4 + iy;
    w4 = make_float4((1.f - fx) * win, fx * win, fy, 0.f);
    return true;
}

__global__ void hist_kernel(const float* __restrict__ rel_pos,
                            const int* __restrict__ receivers,
                            const int* __restrict__ ws_ptr,
                            int* __restrict__ cnt) {
    int e = blockIdx.x * blockDim.x + threadIdx.x;
    if (e >= NEDGE) return;
    int cell; float4 w4;
    if (edge_geom(rel_pos, ws_ptr, e, cell, w4))
        atomicAdd(&cnt[receivers[e]], 1);
}

// one block, 1024 threads: exclusive scan of 40000 counts -> rowptr[40001]
__global__ __launch_bounds__(1024) void scan_kernel(const int* __restrict__ cnt,
                                                    int* __restrict__ rowptr) {
    __shared__ int part[1024];
    int t = threadIdx.x;
    const int CHUNK = 40;
    int base = t * CHUNK;
    int s = 0;
    if (t < 1000)
        for (int i = 0; i < CHUNK; ++i) s += cnt[base + i];
    part[t] = s;
    __syncthreads();
    for (int off = 1; off < 1024; off <<= 1) {
        int v = (t >= off) ? part[t - off] : 0;
        __syncthreads();
        part[t] += v;
        __syncthreads();
    }
    int excl = (t == 0) ? 0 : part[t - 1];
    if (t < 1000) {
        int run = excl;
        for (int i = 0; i < CHUNK; ++i) { rowptr[base + i] = run; run += cnt[base + i]; }
        if (t == 999) rowptr[NPTS] = run;
    }
}

// Packed 16B edge record: {sender|cell<<16, bf16(wx0)|bf16(wx1)<<16, f32 fy, 0}
__global__ void fill_kernel(const float* __restrict__ rel_pos,
                            const int* __restrict__ receivers,
                            const int* __restrict__ senders,
                            const int* __restrict__ ws_ptr,
                            const int* __restrict__ rowptr,
                            int* __restrict__ cursor,
                            uint4* __restrict__ ec) {
    int e = blockIdx.x * blockDim.x + threadIdx.x;
    if (e >= NEDGE) return;
    int cell; float4 w4;
    if (!edge_geom(rel_pos, ws_ptr, e, cell, w4)) return;
    int recv = receivers[e];
    int pos = rowptr[recv] + atomicAdd(&cursor[recv], 1);
    unsigned meta = (unsigned)senders[e] | ((unsigned)cell << 16);
    unsigned wx = (unsigned)f2bf(w4.x) | ((unsigned)f2bf(w4.y) << 16);
    ec[pos] = make_uint4(meta, wx, __float_as_uint(w4.z), 0u);
}

// ===========================================================================
// Merged W repack into bf16 MFMA B-fragment layout:
// Wp[((cb*nKS+ks)*64+l)*8+j] = bf16(W[ks*32+(l>>4)*8+j][cb*16+(l&15)])
// ===========================================================================
__global__ void pack_all_kernel(const float* __restrict__ W1, const float* __restrict__ W2,
                                const float* __restrict__ W3, const float* __restrict__ W4,
                                unsigned short* __restrict__ Wp1, unsigned short* __restrict__ Wp2,
                                unsigned short* __restrict__ Wp3, unsigned short* __restrict__ Wp4) {
    int idx = blockIdx.x * 256 + threadIdx.x;
    const float* W; unsigned short* Wp; int M, COUT, base;
    if (idx < 65536)       { W = W1; Wp = Wp1; M = 1024; COUT = 64; base = 0; }
    else if (idx < 98304)  { W = W2; Wp = Wp2; M = 1024; COUT = 32; base = 65536; }
    else if (idx < 131072) { W = W3; Wp = Wp3; M = 512;  COUT = 64; base = 98304; }
    else if (idx < 163840) { W = W4; Wp = Wp4; M = 1024; COUT = 32; base = 131072; }
    else return;
    int i = idx - base;
    int nKS = M / 32;
    int j = i & 7, l = (i >> 3) & 63, t = i >> 9;
    int ks = t % nKS, cb = t / nKS;
    int m = ks * 32 + (l >> 4) * 8 + j;
    int col = cb * 16 + (l & 15);
    Wp[i] = f2bf(W[(size_t)m * COUT + col]);
}

// ===========================================================================
// Per-edge register accumulation (slot layout, packed 16B record).
// ===========================================================================
template <int VEC>
__device__ __forceinline__ void do_edge(bool act, int e,
                                        const uint4* __restrict__ ec,
                                        const float* __restrict__ fbase,
                                        int fstride, float acc[16][VEC]) {
    uint4 r = ec[e];
    int sender = act ? (int)(r.x & 0xFFFFu) : 0;
    int cell = (int)(r.x >> 16);
    float wx0 = act ? bflo(r.y) : 0.f;
    float wx1 = act ? bfhi(r.y) : 0.f;
    float fy = __uint_as_float(r.z);
    int ix = cell >> 2, iy = cell & 3;
    float wy0 = 1.f - fy, wy1 = fy;
    float wxv[4], wyv[4];
#pragma unroll
    for (int c = 0; c < 4; ++c) {
        wxv[c] = (c == ix) ? wx0 : ((c == ix + 1) ? wx1 : 0.f);
        wyv[c] = (c == iy) ? wy0 : ((c == iy + 1) ? wy1 : 0.f);
    }
    float f[VEC];
    const float* fp = fbase + (size_t)sender * fstride;
    if constexpr (VEC == 4) {
        float4 v = *(const float4*)fp;
        f[0] = v.x; f[1] = v.y; f[2] = v.z; f[3] = v.w;
    } else {
        float2 v = *(const float2*)fp;
        f[0] = v.x; f[1] = v.y;
    }
#pragma unroll
    for (int cx = 0; cx < 4; ++cx) {
        float wxc = wxv[cx];
#pragma unroll
        for (int cy = 0; cy < 4; ++cy) {
            float wc = wxc * wyv[cy];
#pragma unroll
            for (int j = 0; j < VEC; ++j)
                acc[cx * 4 + cy][j] = fmaf(wc, f[j], acc[cx * 4 + cy][j]);
        }
    }
}

// ===========================================================================
// Fused cconv layer (r17 structure: 256 thr, slot layout, MFMA phase 2,
// fused BN partial stats). MODE 0: feat [N][CIN]; MODE 1: concat(x,y).
// ===========================================================================
template <int CIN, int COUT, int MODE>
__global__ __launch_bounds__(256, 4) void fused_layer(const float* __restrict__ feat,
                                                      const float* __restrict__ xin,
                                                      const float* __restrict__ yin,
                                                      const uint4* __restrict__ ec,
                                                      const int* __restrict__ rowptr,
                                                      const unsigned short* __restrict__ Wp,
                                                      const float* __restrict__ a,
                                                      float* __restrict__ P,
                                                      float* __restrict__ part) {
    constexpr int RB = 16;
    constexpr int M = 16 * CIN;
    constexpr int LDB = M + 8;
    constexpr int nKS = M / 32;
    constexpr int VEC = CIN / 16;
    constexpr int CT = COUT / 16;
    __shared__ short S_bf[RB * LDB];
    __shared__ float Rred[CT == 2 ? 512 : 4];

    int tid = threadIdx.x;
    int lane = tid & 63;
    int wave = tid >> 6;
    int slot = lane >> 4;
    int q = lane & 15;
    int rloc = wave * 4 + slot;
    int rglob = blockIdx.x * RB + rloc;
    int rs = rowptr[rglob];
    int deg = rowptr[rglob + 1] - rs;
    int md = deg;
    md = max(md, __shfl_xor(md, 16));
    md = max(md, __shfl_xor(md, 32));

    const float* fbase;
    int fstride;
    if constexpr (MODE == 1) {
        fbase = (q < 8) ? (xin + q * VEC) : (yin + (q - 8) * VEC);
        fstride = 32;
    } else {
        fbase = feat + q * VEC;
        fstride = CIN;
    }

    float acc[16][VEC];
#pragma unroll
    for (int cc = 0; cc < 16; ++cc)
#pragma unroll
        for (int j = 0; j < VEC; ++j) acc[cc][j] = 0.f;

#pragma unroll 2
    for (int k = 0; k < md; ++k) {
        bool act = k < deg;
        do_edge<VEC>(act, rs + (act ? k : 0), ec, fbase, fstride, acc);
    }

    // --- handoff: acc -> bf16 LDS rows ---
    {
        short* srow = &S_bf[rloc * LDB + q * VEC];
#pragma unroll
        for (int cc = 0; cc < 16; ++cc) {
            if constexpr (VEC == 4) {
                unsigned lo = (unsigned)f2bf(acc[cc][0]) | ((unsigned)f2bf(acc[cc][1]) << 16);
                unsigned hi = (unsigned)f2bf(acc[cc][2]) | ((unsigned)f2bf(acc[cc][3]) << 16);
                *(uint2*)(srow + cc * CIN) = make_uint2(lo, hi);
            } else {
                unsigned lo = (unsigned)f2bf(acc[cc][0]) | ((unsigned)f2bf(acc[cc][1]) << 16);
                *(unsigned*)(srow + cc * CIN) = lo;
            }
        }
    }
    __syncthreads();

    // --- phase 2: MFMA GEMM ---
    int row16 = lane & 15;
    int kgrp = lane >> 4;
    f32x4 c = {0.f, 0.f, 0.f, 0.f};
    int cb, ks0;
    constexpr int KS_PER = (CT == 4) ? nKS : nKS / 2;
    if constexpr (CT == 4) { cb = wave; ks0 = 0; }
    else { cb = wave & 1; ks0 = (wave >> 1) * KS_PER; }

    const short* abase = &S_bf[row16 * LDB + kgrp * 8];
    const bf16x8* wfrag = (const bf16x8*)Wp;
    size_t wbase = (size_t)(cb * nKS + ks0) * 64 + lane;
#pragma unroll 8
    for (int kk = 0; kk < KS_PER; ++kk) {
        bf16x8 af = *(const bf16x8*)(abase + (size_t)(ks0 + kk) * 32);
        bf16x8 bf = wfrag[wbase + (size_t)kk * 64];
        c = __builtin_amdgcn_mfma_f32_16x16x32_bf16(af, bf, c, 0, 0, 0);
    }

    // --- write out + per-block BN partials ---
    if constexpr (CT == 2) {
        if (wave >= 2) {
#pragma unroll
            for (int i = 0; i < 4; ++i)
                Rred[cb * 256 + (kgrp * 4 + i) * 16 + row16] = c[i];
        }
        __syncthreads();
        if (wave < 2) {
            float sp = 0.f, sq = 0.f;
#pragma unroll
            for (int i = 0; i < 4; ++i) {
                int row = kgrp * 4 + i;
                int n = blockIdx.x * RB + row;
                float v = a[n] * (c[i] + Rred[cb * 256 + row * 16 + row16]);
                P[(size_t)n * COUT + cb * 16 + row16] = v;
                sp += v; sq += v * v;
            }
            sp += __shfl_xor(sp, 16); sp += __shfl_xor(sp, 32);
            sq += __shfl_xor(sq, 16); sq += __shfl_xor(sq, 32);
            if (kgrp == 0) {
                part[(size_t)blockIdx.x * 2 * COUT + cb * 16 + row16] = sp;
                part[(size_t)blockIdx.x * 2 * COUT + COUT + cb * 16 + row16] = sq;
            }
        }
    } else {
        float sp = 0.f, sq = 0.f;
#pragma unroll
        for (int i = 0; i < 4; ++i) {
            int row = kgrp * 4 + i;
            int n = blockIdx.x * RB + row;
            float v = a[n] * c[i];
            P[(size_t)n * COUT + cb * 16 + row16] = v;
            sp += v; sq += v * v;
        }
        sp += __shfl_xor(sp, 16); sp += __shfl_xor(sp, 32);
        sq += __shfl_xor(sq, 16); sq += __shfl_xor(sq, 32);
        if (kgrp == 0) {
            part[(size_t)blockIdx.x * 2 * COUT + cb * 16 + row16] = sp;
            part[(size_t)blockIdx.x * 2 * COUT + COUT + cb * 16 + row16] = sq;
        }
    }
}

// ===========================================================================
// BN finalize: 1024 threads reduce 2500 per-block partials -> scale/shift.
// ===========================================================================
template <int COUT>
__global__ __launch_bounds__(1024) void finalize_bn_kernel(const float* __restrict__ part,
                                                           const float* __restrict__ g,
                                                           const float* __restrict__ b,
                                                           float* __restrict__ scb) {
    constexpr int C2 = 2 * COUT;
    constexpr int NG = 1024 / C2;         // 8 (COUT=64) or 16 (COUT=32)
    constexpr int NB = NPTS / 16;         // 2500
    constexpr int PER = (NB + NG - 1) / NG;
    __shared__ float ls[1024];
    int tid = threadIdx.x;
    int d = tid % C2;
    int gi = tid / C2;
    float s = 0.f;
    int k0 = gi * PER;
    int k1 = k0 + PER > NB ? NB : k0 + PER;
    for (int k = k0; k < k1; ++k) s += part[(size_t)k * C2 + d];
    ls[tid] = s;
    __syncthreads();
    if (tid < C2) {
        float tot = ls[tid];
        for (int g2 = 1; g2 < NG; ++g2) tot += ls[tid + g2 * C2];
        ls[tid] = tot;
    }
    __syncthreads();
    if (tid < COUT) {
        float sum = ls[tid], ssq = ls[COUT + tid];
        float mean = sum / (float)NPTS;
        float var = ssq / (float)NPTS - mean * mean;
        float inv = rsqrtf(var + BN_EPS);
        float scale = inv * g[tid];
        scb[tid] = scale;
        scb[COUT + tid] = b[tid] - mean * scale;
    }
}

template <int COUT>
__global__ void apply_relu_kernel(float* __restrict__ P, const float* __restrict__ scb) {
    int t = blockIdx.x * blockDim.x + threadIdx.x;
    if (t >= NPTS * COUT) return;
    int d = t % COUT;
    float v = P[t] * scb[d] + scb[COUT + d];
    P[t] = fmaxf(v, 0.0f);
}

__global__ void apply_sigmix_kernel(const float* __restrict__ P,
                                    const float* __restrict__ scb,
                                    const float* __restrict__ x,
                                    const float* __restrict__ y,
                                    float* __restrict__ out) {
    int t = blockIdx.x * blockDim.x + threadIdx.x;
    if (t >= NPTS * 32) return;
    int d = t & 31;
    float v = P[t] * scb[d] + scb[32 + d];
    float w = 1.0f / (1.0f + expf(-v));
    out[t] = 2.0f * x[t] * w + 2.0f * y[t] * (1.0f - w);
}

extern "C" void kernel_launch(void* const* d_in, const int* in_sizes, int n_in,
                              void* d_out, int out_size, void* d_ws, size_t ws_size,
                              hipStream_t stream) {
    const float* x = (const float*)d_in[0];
    const float* y = (const float*)d_in[1];
    const int* senders = (const int*)d_in[2];
    const int* receivers = (const int*)d_in[3];
    const float* rel_pos = (const float*)d_in[4];
    const int* ws_ptr = (const int*)d_in[5];
    const float* a = (const float*)d_in[6];
    const float* W1 = (const float*)d_in[7];
    const float* W2 = (const float*)d_in[8];
    const float* W3 = (const float*)d_in[9];
    const float* W4 = (const float*)d_in[10];
    const float* g1 = (const float*)d_in[11];
    const float* b1 = (const float*)d_in[12];
    const float* g2 = (const float*)d_in[13];
    const float* b2 = (const float*)d_in[14];
    const float* g3 = (const float*)d_in[15];
    const float* b3 = (const float*)d_in[16];
    const float* g4 = (const float*)d_in[17];
    const float* b4 = (const float*)d_in[18];

    char* ws = (char*)d_ws;
    size_t off = 0;
    auto alloc = [&](size_t bytes) -> void* {
        void* p = ws + off;
        off += (bytes + 255) & ~(size_t)255;
        return p;
    };
    int* cnt = (int*)alloc((size_t)NPTS * sizeof(int));
    int* cursor = (int*)alloc((size_t)NPTS * sizeof(int));
    int* rowptr = (int*)alloc((size_t)(NPTS + 1) * sizeof(int));
    uint4* ec = (uint4*)alloc((size_t)(NEDGE + 4) * sizeof(uint4));
    float* xa = (float*)alloc((size_t)NPTS * 64 * sizeof(float));  // P3
    float* P1 = (float*)alloc((size_t)NPTS * 64 * sizeof(float));
    float* P2 = (float*)alloc((size_t)NPTS * 32 * sizeof(float));  // also P4
    float* xo = (float*)alloc((size_t)NPTS * 32 * sizeof(float));
    float* part = (float*)alloc((size_t)(NPTS / 16) * 128 * sizeof(float));
    float* scb = (float*)alloc(2 * 64 * sizeof(float));
    unsigned short* Wp1 = (unsigned short*)alloc((size_t)1024 * 64 * 2);
    unsigned short* Wp2 = (unsigned short*)alloc((size_t)1024 * 32 * 2);
    unsigned short* Wp3 = (unsigned short*)alloc((size_t)512 * 64 * 2);
    unsigned short* Wp4 = (unsigned short*)alloc((size_t)1024 * 32 * 2);
    (void)ws_size; (void)in_sizes; (void)n_in; (void)out_size;

    // --- prologue ---
    pack_all_kernel<<<640, 256, 0, stream>>>(W1, W2, W3, W4, Wp1, Wp2, Wp3, Wp4);
    hipMemsetAsync(cnt, 0, (size_t)2 * NPTS * sizeof(int), stream);  // cnt+cursor
    hist_kernel<<<(NEDGE + 255) / 256, 256, 0, stream>>>(rel_pos, receivers, ws_ptr, cnt);
    scan_kernel<<<1, 1024, 0, stream>>>(cnt, rowptr);
    fill_kernel<<<(NEDGE + 255) / 256, 256, 0, stream>>>(rel_pos, receivers, senders, ws_ptr,
                                                         rowptr, cursor, ec);

    // Layer 1
    fused_layer<64, 64, 1><<<NPTS / 16, 256, 0, stream>>>(nullptr, x, y, ec, rowptr,
                                                          Wp1, a, P1, part);
    finalize_bn_kernel<64><<<1, 1024, 0, stream>>>(part, g1, b1, scb);
    apply_relu_kernel<64><<<(NPTS * 64 + 255) / 256, 256, 0, stream>>>(P1, scb);

    // Layer 2
    fused_layer<64, 32, 0><<<NPTS / 16, 256, 0, stream>>>(P1, nullptr, nullptr, ec, rowptr,
                                                          Wp2, a, P2, part);
    finalize_bn_kernel<32><<<1, 1024, 0, stream>>>(part, g2, b2, scb);
    apply_sigmix_kernel<<<(NPTS * 32 + 255) / 256, 256, 0, stream>>>(P2, scb, x, y, xo);

    // Layer 3
    fused_layer<32, 64, 0><<<NPTS / 16, 256, 0, stream>>>(xo, nullptr, nullptr, ec, rowptr,
                                                          Wp3, a, xa, part);
    finalize_bn_kernel<64><<<1, 1024, 0, stream>>>(part, g3, b3, scb);
    apply_relu_kernel<64><<<(NPTS * 64 + 255) / 256, 256, 0, stream>>>(xa, scb);

    // Layer 4
    fused_layer<64, 32, 0><<<NPTS / 16, 256, 0, stream>>>(xa, nullptr, nullptr, ec, rowptr,
                                                          Wp4, a, P2, part);
    finalize_bn_kernel<32><<<1, 1024, 0, stream>>>(part, g4, b4, scb);
    apply_sigmix_kernel<<<(NPTS * 32 + 255) / 256, 256, 0, stream>>>(P2, scb, x, y, (float*)d_out);
}

// Round 20
// 362.633 us; speedup vs baseline: 1.7844x; 1.7296x over previous
//
#include <hip/hip_runtime.h>

#define NPTS 40000
#define NEDGE 1000000
#define BN_EPS 1e-5f

typedef short bf16x8 __attribute__((ext_vector_type(8)));
typedef float f32x4 __attribute__((ext_vector_type(4)));

__device__ __forceinline__ unsigned short f2bf(float x) {
    unsigned u = __float_as_uint(x);
    return (unsigned short)((u + 0x7FFFu + ((u >> 16) & 1u)) >> 16);  // RTN-even
}
__device__ __forceinline__ float bflo(unsigned x) { return __uint_as_float(x << 16); }
__device__ __forceinline__ float bfhi(unsigned x) { return __uint_as_float(x & 0xFFFF0000u); }

// ===========================================================================
// Edge geometry: validity + cell + factorized weights.
// ===========================================================================
__device__ inline bool edge_geom(const float* rel_pos, const int* ws_ptr, int e,
                                 int& cell, float4& w4) {
    float ws = (float)ws_ptr[0];
    float inv_ws = 1.0f / ws;
    float ux = rel_pos[2 * e] * inv_ws;
    float uy = rel_pos[2 * e + 1] * inv_ws;
    float q = 1.0f - (ux * ux + uy * uy);
    if (!(q > 0.0f)) return false;
    float win = q * q * q;
    float gx = fminf(fmaxf((ux + 1.0f) * 1.5f, 0.0f), 3.0f);
    float gy = fminf(fmaxf((uy + 1.0f) * 1.5f, 0.0f), 3.0f);
    int ix = (int)floorf(gx); ix = ix < 0 ? 0 : (ix > 2 ? 2 : ix);
    int iy = (int)floorf(gy); iy = iy < 0 ? 0 : (iy > 2 ? 2 : iy);
    float fx = gx - (float)ix;
    float fy = gy - (float)iy;
    cell = ix * 4 + iy;
    w4 = make_float4((1.f - fx) * win, fx * win, fy, 0.f);
    return true;
}

__global__ void hist_kernel(const float* __restrict__ rel_pos,
                            const int* __restrict__ receivers,
                            const int* __restrict__ ws_ptr,
                            int* __restrict__ cnt) {
    int e = blockIdx.x * blockDim.x + threadIdx.x;
    if (e >= NEDGE) return;
    int cell; float4 w4;
    if (edge_geom(rel_pos, ws_ptr, e, cell, w4))
        atomicAdd(&cnt[receivers[e]], 1);
}

// one block, 1024 threads: exclusive scan of 40000 counts -> rowptr[40001]
__global__ __launch_bounds__(1024) void scan_kernel(const int* __restrict__ cnt,
                                                    int* __restrict__ rowptr) {
    __shared__ int part[1024];
    int t = threadIdx.x;
    const int CHUNK = 40;
    int base = t * CHUNK;
    int s = 0;
    if (t < 1000)
        for (int i = 0; i < CHUNK; ++i) s += cnt[base + i];
    part[t] = s;
    __syncthreads();
    for (int off = 1; off < 1024; off <<= 1) {
        int v = (t >= off) ? part[t - off] : 0;
        __syncthreads();
        part[t] += v;
        __syncthreads();
    }
    int excl = (t == 0) ? 0 : part[t - 1];
    if (t < 1000) {
        int run = excl;
        for (int i = 0; i < CHUNK; ++i) { rowptr[base + i] = run; run += cnt[base + i]; }
        if (t == 999) rowptr[NPTS] = run;
    }
}

// Packed 16B edge record: {sender|cell<<16, bf16(wx0)|bf16(wx1)<<16, f32 fy, 0}
__global__ void fill_kernel(const float* __restrict__ rel_pos,
                            const int* __restrict__ receivers,
                            const int* __restrict__ senders,
                            const int* __restrict__ ws_ptr,
                            const int* __restrict__ rowptr,
                            int* __restrict__ cursor,
                            uint4* __restrict__ ec) {
    int e = blockIdx.x * blockDim.x + threadIdx.x;
    if (e >= NEDGE) return;
    int cell; float4 w4;
    if (!edge_geom(rel_pos, ws_ptr, e, cell, w4)) return;
    int recv = receivers[e];
    int pos = rowptr[recv] + atomicAdd(&cursor[recv], 1);
    unsigned meta = (unsigned)senders[e] | ((unsigned)cell << 16);
    unsigned wx = (unsigned)f2bf(w4.x) | ((unsigned)f2bf(w4.y) << 16);
    ec[pos] = make_uint4(meta, wx, __float_as_uint(w4.z), 0u);
}

// ===========================================================================
// Merged W repack into bf16 MFMA B-fragment layout.
// ===========================================================================
__global__ void pack_all_kernel(const float* __restrict__ W1, const float* __restrict__ W2,
                                const float* __restrict__ W3, const float* __restrict__ W4,
                                unsigned short* __restrict__ Wp1, unsigned short* __restrict__ Wp2,
                                unsigned short* __restrict__ Wp3, unsigned short* __restrict__ Wp4) {
    int idx = blockIdx.x * 256 + threadIdx.x;
    const float* W; unsigned short* Wp; int M, COUT, base;
    if (idx < 65536)       { W = W1; Wp = Wp1; M = 1024; COUT = 64; base = 0; }
    else if (idx < 98304)  { W = W2; Wp = Wp2; M = 1024; COUT = 32; base = 65536; }
    else if (idx < 131072) { W = W3; Wp = Wp3; M = 512;  COUT = 64; base = 98304; }
    else if (idx < 163840) { W = W4; Wp = Wp4; M = 1024; COUT = 32; base = 131072; }
    else return;
    int i = idx - base;
    int nKS = M / 32;
    int j = i & 7, l = (i >> 3) & 63, t = i >> 9;
    int ks = t % nKS, cb = t / nKS;
    int m = ks * 32 + (l >> 4) * 8 + j;
    int col = cb * 16 + (l & 15);
    Wp[i] = f2bf(W[(size_t)m * COUT + col]);
}

// ===========================================================================
// Per-edge register accumulation (slot layout, packed 16B record).
// ===========================================================================
template <int VEC>
__device__ __forceinline__ void do_edge(bool act, int e,
                                        const uint4* __restrict__ ec,
                                        const float* __restrict__ fbase,
                                        int fstride, float acc[16][VEC]) {
    uint4 r = ec[e];
    int sender = act ? (int)(r.x & 0xFFFFu) : 0;
    int cell = (int)(r.x >> 16);
    float wx0 = act ? bflo(r.y) : 0.f;
    float wx1 = act ? bfhi(r.y) : 0.f;
    float fy = __uint_as_float(r.z);
    int ix = cell >> 2, iy = cell & 3;
    float wy0 = 1.f - fy, wy1 = fy;
    float wxv[4], wyv[4];
#pragma unroll
    for (int c = 0; c < 4; ++c) {
        wxv[c] = (c == ix) ? wx0 : ((c == ix + 1) ? wx1 : 0.f);
        wyv[c] = (c == iy) ? wy0 : ((c == iy + 1) ? wy1 : 0.f);
    }
    float f[VEC];
    const float* fp = fbase + (size_t)sender * fstride;
    if constexpr (VEC == 4) {
        float4 v = *(const float4*)fp;
        f[0] = v.x; f[1] = v.y; f[2] = v.z; f[3] = v.w;
    } else {
        float2 v = *(const float2*)fp;
        f[0] = v.x; f[1] = v.y;
    }
#pragma unroll
    for (int cx = 0; cx < 4; ++cx) {
        float wxc = wxv[cx];
#pragma unroll
        for (int cy = 0; cy < 4; ++cy) {
            float wc = wxc * wyv[cy];
#pragma unroll
            for (int j = 0; j < VEC; ++j)
                acc[cx * 4 + cy][j] = fmaf(wc, f[j], acc[cx * 4 + cy][j]);
        }
    }
}

// ===========================================================================
// Fused cconv layer (256 thr, slot layout, MFMA phase 2, fused BN partials).
// ===========================================================================
template <int CIN, int COUT, int MODE>
__global__ __launch_bounds__(256, 4) void fused_layer(const float* __restrict__ feat,
                                                      const float* __restrict__ xin,
                                                      const float* __restrict__ yin,
                                                      const uint4* __restrict__ ec,
                                                      const int* __restrict__ rowptr,
                                                      const unsigned short* __restrict__ Wp,
                                                      const float* __restrict__ a,
                                                      float* __restrict__ P,
                                                      float* __restrict__ part) {
    constexpr int RB = 16;
    constexpr int M = 16 * CIN;
    constexpr int LDB = M + 8;
    constexpr int nKS = M / 32;
    constexpr int VEC = CIN / 16;
    constexpr int CT = COUT / 16;
    __shared__ short S_bf[RB * LDB];
    __shared__ float Rred[CT == 2 ? 512 : 4];

    int tid = threadIdx.x;
    int lane = tid & 63;
    int wave = tid >> 6;
    int slot = lane >> 4;
    int q = lane & 15;
    int rloc = wave * 4 + slot;
    int rglob = blockIdx.x * RB + rloc;
    int rs = rowptr[rglob];
    int deg = rowptr[rglob + 1] - rs;
    int md = deg;
    md = max(md, __shfl_xor(md, 16));
    md = max(md, __shfl_xor(md, 32));

    const float* fbase;
    int fstride;
    if constexpr (MODE == 1) {
        fbase = (q < 8) ? (xin + q * VEC) : (yin + (q - 8) * VEC);
        fstride = 32;
    } else {
        fbase = feat + q * VEC;
        fstride = CIN;
    }

    float acc[16][VEC];
#pragma unroll
    for (int cc = 0; cc < 16; ++cc)
#pragma unroll
        for (int j = 0; j < VEC; ++j) acc[cc][j] = 0.f;

#pragma unroll 2
    for (int k = 0; k < md; ++k) {
        bool act = k < deg;
        do_edge<VEC>(act, rs + (act ? k : 0), ec, fbase, fstride, acc);
    }

    // --- handoff: acc -> bf16 LDS rows ---
    {
        short* srow = &S_bf[rloc * LDB + q * VEC];
#pragma unroll
        for (int cc = 0; cc < 16; ++cc) {
            if constexpr (VEC == 4) {
                unsigned lo = (unsigned)f2bf(acc[cc][0]) | ((unsigned)f2bf(acc[cc][1]) << 16);
                unsigned hi = (unsigned)f2bf(acc[cc][2]) | ((unsigned)f2bf(acc[cc][3]) << 16);
                *(uint2*)(srow + cc * CIN) = make_uint2(lo, hi);
            } else {
                unsigned lo = (unsigned)f2bf(acc[cc][0]) | ((unsigned)f2bf(acc[cc][1]) << 16);
                *(unsigned*)(srow + cc * CIN) = lo;
            }
        }
    }
    __syncthreads();

    // --- phase 2: MFMA GEMM ---
    int row16 = lane & 15;
    int kgrp = lane >> 4;
    f32x4 c = {0.f, 0.f, 0.f, 0.f};
    int cb, ks0;
    constexpr int KS_PER = (CT == 4) ? nKS : nKS / 2;
    if constexpr (CT == 4) { cb = wave; ks0 = 0; }
    else { cb = wave & 1; ks0 = (wave >> 1) * KS_PER; }

    const short* abase = &S_bf[row16 * LDB + kgrp * 8];
    const bf16x8* wfrag = (const bf16x8*)Wp;
    size_t wbase = (size_t)(cb * nKS + ks0) * 64 + lane;
#pragma unroll 8
    for (int kk = 0; kk < KS_PER; ++kk) {
        bf16x8 af = *(const bf16x8*)(abase + (size_t)(ks0 + kk) * 32);
        bf16x8 bf = wfrag[wbase + (size_t)kk * 64];
        c = __builtin_amdgcn_mfma_f32_16x16x32_bf16(af, bf, c, 0, 0, 0);
    }

    // --- write out + per-block BN partials ---
    if constexpr (CT == 2) {
        if (wave >= 2) {
#pragma unroll
            for (int i = 0; i < 4; ++i)
                Rred[cb * 256 + (kgrp * 4 + i) * 16 + row16] = c[i];
        }
        __syncthreads();
        if (wave < 2) {
            float sp = 0.f, sq = 0.f;
#pragma unroll
            for (int i = 0; i < 4; ++i) {
                int row = kgrp * 4 + i;
                int n = blockIdx.x * RB + row;
                float v = a[n] * (c[i] + Rred[cb * 256 + row * 16 + row16]);
                P[(size_t)n * COUT + cb * 16 + row16] = v;
                sp += v; sq += v * v;
            }
            sp += __shfl_xor(sp, 16); sp += __shfl_xor(sp, 32);
            sq += __shfl_xor(sq, 16); sq += __shfl_xor(sq, 32);
            if (kgrp == 0) {
                part[(size_t)blockIdx.x * 2 * COUT + cb * 16 + row16] = sp;
                part[(size_t)blockIdx.x * 2 * COUT + COUT + cb * 16 + row16] = sq;
            }
        }
    } else {
        float sp = 0.f, sq = 0.f;
#pragma unroll
        for (int i = 0; i < 4; ++i) {
            int row = kgrp * 4 + i;
            int n = blockIdx.x * RB + row;
            float v = a[n] * c[i];
            P[(size_t)n * COUT + cb * 16 + row16] = v;
            sp += v; sq += v * v;
        }
        sp += __shfl_xor(sp, 16); sp += __shfl_xor(sp, 32);
        sq += __shfl_xor(sq, 16); sq += __shfl_xor(sq, 32);
        if (kgrp == 0) {
            part[(size_t)blockIdx.x * 2 * COUT + cb * 16 + row16] = sp;
            part[(size_t)blockIdx.x * 2 * COUT + COUT + cb * 16 + row16] = sq;
        }
    }
}

// ===========================================================================
// BN reduction, stage 1: 64 blocks x 256 thr, each block sums 40 partial
// rows -> part2[64][2*COUT]. Static bounds -> unrolled, pipelined loads
// (r19 lesson: a runtime-clamped trip count serialized the loads, 92 us).
// ===========================================================================
template <int COUT>
__global__ __launch_bounds__(256) void bn_mid_kernel(const float* __restrict__ part,
                                                     float* __restrict__ part2) {
    constexpr int C2 = 2 * COUT;
    constexpr int NG = 256 / C2;          // 2 (COUT=64) or 4 (COUT=32)
    constexpr int NB = NPTS / 16;         // 2500
    constexpr int NRB = (NB + 63) / 64;   // 40 rows per block
    __shared__ float ls[256];
    int tid = threadIdx.x;
    int d = tid % C2;
    int gi = tid / C2;
    int k0 = blockIdx.x * NRB;
    float s = 0.f;
#pragma unroll
    for (int j = 0; j < NRB / NG + 1; ++j) {
        int k = k0 + gi + j * NG;
        bool ok = (gi + j * NG < NRB) && (k < NB);
        s += ok ? part[(size_t)k * C2 + d] : 0.f;
    }
    ls[tid] = s;
    __syncthreads();
    if (gi == 0) {
        float tot = s;
#pragma unroll
        for (int g2 = 1; g2 < NG; ++g2) tot += ls[tid + g2 * C2];
        part2[(size_t)blockIdx.x * C2 + d] = tot;
    }
}

// Stage 2: 1 block x 1024 thr over 64 rows (static 8 or 4 iters) -> scale/shift
template <int COUT>
__global__ __launch_bounds__(1024) void bn_fin_kernel(const float* __restrict__ part2,
                                                      const float* __restrict__ g,
                                                      const float* __restrict__ b,
                                                      float* __restrict__ scb) {
    constexpr int C2 = 2 * COUT;
    constexpr int NG = 1024 / C2;         // 8 or 16
    __shared__ float ls[1024];
    int tid = threadIdx.x;
    int d = tid % C2;
    int gi = tid / C2;
    float s = 0.f;
#pragma unroll
    for (int j = 0; j < 64 / NG; ++j)
        s += part2[(size_t)(gi + j * NG) * C2 + d];
    ls[tid] = s;
    __syncthreads();
    if (tid < C2) {
        float tot = ls[tid];
#pragma unroll
        for (int g2 = 1; g2 < NG; ++g2) tot += ls[tid + g2 * C2];
        ls[tid] = tot;
    }
    __syncthreads();
    if (tid < COUT) {
        float sum = ls[tid], ssq = ls[COUT + tid];
        float mean = sum / (float)NPTS;
        float var = ssq / (float)NPTS - mean * mean;
        float inv = rsqrtf(var + BN_EPS);
        float scale = inv * g[tid];
        scb[tid] = scale;
        scb[COUT + tid] = b[tid] - mean * scale;
    }
}

template <int COUT>
__global__ void apply_relu_kernel(float* __restrict__ P, const float* __restrict__ scb) {
    int t = blockIdx.x * blockDim.x + threadIdx.x;
    if (t >= NPTS * COUT) return;
    int d = t % COUT;
    float v = P[t] * scb[d] + scb[COUT + d];
    P[t] = fmaxf(v, 0.0f);
}

__global__ void apply_sigmix_kernel(const float* __restrict__ P,
                                    const float* __restrict__ scb,
                                    const float* __restrict__ x,
                                    const float* __restrict__ y,
                                    float* __restrict__ out) {
    int t = blockIdx.x * blockDim.x + threadIdx.x;
    if (t >= NPTS * 32) return;
    int d = t & 31;
    float v = P[t] * scb[d] + scb[32 + d];
    float w = 1.0f / (1.0f + expf(-v));
    out[t] = 2.0f * x[t] * w + 2.0f * y[t] * (1.0f - w);
}

extern "C" void kernel_launch(void* const* d_in, const int* in_sizes, int n_in,
                              void* d_out, int out_size, void* d_ws, size_t ws_size,
                              hipStream_t stream) {
    const float* x = (const float*)d_in[0];
    const float* y = (const float*)d_in[1];
    const int* senders = (const int*)d_in[2];
    const int* receivers = (const int*)d_in[3];
    const float* rel_pos = (const float*)d_in[4];
    const int* ws_ptr = (const int*)d_in[5];
    const float* a = (const float*)d_in[6];
    const float* W1 = (const float*)d_in[7];
    const float* W2 = (const float*)d_in[8];
    const float* W3 = (const float*)d_in[9];
    const float* W4 = (const float*)d_in[10];
    const float* g1 = (const float*)d_in[11];
    const float* b1 = (const float*)d_in[12];
    const float* g2 = (const float*)d_in[13];
    const float* b2 = (const float*)d_in[14];
    const float* g3 = (const float*)d_in[15];
    const float* b3 = (const float*)d_in[16];
    const float* g4 = (const float*)d_in[17];
    const float* b4 = (const float*)d_in[18];

    char* ws = (char*)d_ws;
    size_t off = 0;
    auto alloc = [&](size_t bytes) -> void* {
        void* p = ws + off;
        off += (bytes + 255) & ~(size_t)255;
        return p;
    };
    int* cnt = (int*)alloc((size_t)NPTS * sizeof(int));
    int* cursor = (int*)alloc((size_t)NPTS * sizeof(int));
    int* rowptr = (int*)alloc((size_t)(NPTS + 1) * sizeof(int));
    uint4* ec = (uint4*)alloc((size_t)(NEDGE + 4) * sizeof(uint4));
    float* xa = (float*)alloc((size_t)NPTS * 64 * sizeof(float));  // P3
    float* P1 = (float*)alloc((size_t)NPTS * 64 * sizeof(float));
    float* P2 = (float*)alloc((size_t)NPTS * 32 * sizeof(float));  // also P4
    float* xo = (float*)alloc((size_t)NPTS * 32 * sizeof(float));
    float* part = (float*)alloc((size_t)(NPTS / 16) * 128 * sizeof(float));
    float* part2 = (float*)alloc((size_t)64 * 128 * sizeof(float));
    float* scb = (float*)alloc(2 * 64 * sizeof(float));
    unsigned short* Wp1 = (unsigned short*)alloc((size_t)1024 * 64 * 2);
    unsigned short* Wp2 = (unsigned short*)alloc((size_t)1024 * 32 * 2);
    unsigned short* Wp3 = (unsigned short*)alloc((size_t)512 * 64 * 2);
    unsigned short* Wp4 = (unsigned short*)alloc((size_t)1024 * 32 * 2);
    (void)ws_size; (void)in_sizes; (void)n_in; (void)out_size;

    // --- prologue ---
    pack_all_kernel<<<640, 256, 0, stream>>>(W1, W2, W3, W4, Wp1, Wp2, Wp3, Wp4);
    hipMemsetAsync(cnt, 0, (size_t)2 * NPTS * sizeof(int), stream);  // cnt+cursor
    hist_kernel<<<(NEDGE + 255) / 256, 256, 0, stream>>>(rel_pos, receivers, ws_ptr, cnt);
    scan_kernel<<<1, 1024, 0, stream>>>(cnt, rowptr);
    fill_kernel<<<(NEDGE + 255) / 256, 256, 0, stream>>>(rel_pos, receivers, senders, ws_ptr,
                                                         rowptr, cursor, ec);

    // Layer 1
    fused_layer<64, 64, 1><<<NPTS / 16, 256, 0, stream>>>(nullptr, x, y, ec, rowptr,
                                                          Wp1, a, P1, part);
    bn_mid_kernel<64><<<64, 256, 0, stream>>>(part, part2);
    bn_fin_kernel<64><<<1, 1024, 0, stream>>>(part2, g1, b1, scb);
    apply_relu_kernel<64><<<(NPTS * 64 + 255) / 256, 256, 0, stream>>>(P1, scb);

    // Layer 2
    fused_layer<64, 32, 0><<<NPTS / 16, 256, 0, stream>>>(P1, nullptr, nullptr, ec, rowptr,
                                                          Wp2, a, P2, part);
    bn_mid_kernel<32><<<64, 256, 0, stream>>>(part, part2);
    bn_fin_kernel<32><<<1, 1024, 0, stream>>>(part2, g2, b2, scb);
    apply_sigmix_kernel<<<(NPTS * 32 + 255) / 256, 256, 0, stream>>>(P2, scb, x, y, xo);

    // Layer 3
    fused_layer<32, 64, 0><<<NPTS / 16, 256, 0, stream>>>(xo, nullptr, nullptr, ec, rowptr,
                                                          Wp3, a, xa, part);
    bn_mid_kernel<64><<<64, 256, 0, stream>>>(part, part2);
    bn_fin_kernel<64><<<1, 1024, 0, stream>>>(part2, g3, b3, scb);
    apply_relu_kernel<64><<<(NPTS * 64 + 255) / 256, 256, 0, stream>>>(xa, scb);

    // Layer 4
    fused_layer<64, 32, 0><<<NPTS / 16, 256, 0, stream>>>(xa, nullptr, nullptr, ec, rowptr,
                                                          Wp4, a, P2, part);
    bn_mid_kernel<32><<<64, 256, 0, stream>>>(part, part2);
    bn_fin_kernel<32><<<1, 1024, 0, stream>>>(part2, g4, b4, scb);
    apply_sigmix_kernel<<<(NPTS * 32 + 255) / 256, 256, 0, stream>>>(P2, scb, x, y, (float*)d_out);
}

// Round 21
// 265.532 us; speedup vs baseline: 2.4369x; 1.3657x over previous
//
#include <hip/hip_runtime.h>

#define NPTS 40000
#define NEDGE 1000000
#define BN_EPS 1e-5f

typedef short bf16x8 __attribute__((ext_vector_type(8)));
typedef float f32x4 __attribute__((ext_vector_type(4)));

__device__ __forceinline__ unsigned short f2bf(float x) {
    unsigned u = __float_as_uint(x);
    return (unsigned short)((u + 0x7FFFu + ((u >> 16) & 1u)) >> 16);  // RTN-even
}
__device__ __forceinline__ bf16x8 pack8(unsigned v0, unsigned v1, unsigned v2, unsigned v3,
                                        unsigned v4, unsigned v5, unsigned v6, unsigned v7) {
    uint4 u = make_uint4(v0 | (v1 << 16), v2 | (v3 << 16), v4 | (v5 << 16), v6 | (v7 << 16));
    return __builtin_bit_cast(bf16x8, u);
}

// ===========================================================================
// Edge geometry: validity + cell + corner weights (w00,w01,w10,w11).
// ===========================================================================
__device__ inline bool edge_geom(const float* rel_pos, const int* ws_ptr, int e,
                                 int& cell, float4& w4) {
    float ws = (float)ws_ptr[0];
    float inv_ws = 1.0f / ws;
    float ux = rel_pos[2 * e] * inv_ws;
    float uy = rel_pos[2 * e + 1] * inv_ws;
    float q = 1.0f - (ux * ux + uy * uy);
    if (!(q > 0.0f)) return false;
    float win = q * q * q;
    float gx = fminf(fmaxf((ux + 1.0f) * 1.5f, 0.0f), 3.0f);
    float gy = fminf(fmaxf((uy + 1.0f) * 1.5f, 0.0f), 3.0f);
    int ix = (int)floorf(gx); ix = ix < 0 ? 0 : (ix > 2 ? 2 : ix);
    int iy = (int)floorf(gy); iy = iy < 0 ? 0 : (iy > 2 ? 2 : iy);
    float fx = gx - (float)ix;
    float fy = gy - (float)iy;
    cell = ix * 4 + iy;
    float wx0 = (1.f - fx) * win, wx1 = fx * win;
    float wy0 = 1.f - fy, wy1 = fy;
    w4 = make_float4(wx0 * wy0, wx0 * wy1, wx1 * wy0, wx1 * wy1);
    return true;
}

__global__ void hist_kernel(const float* __restrict__ rel_pos,
                            const int* __restrict__ receivers,
                            const int* __restrict__ ws_ptr,
                            int* __restrict__ cnt) {
    int e = blockIdx.x * blockDim.x + threadIdx.x;
    if (e >= NEDGE) return;
    int cell; float4 w4;
    if (edge_geom(rel_pos, ws_ptr, e, cell, w4))
        atomicAdd(&cnt[receivers[e]], 1);
}

// one block, 1024 threads: exclusive scan of 40000 counts -> rowptr[40001]
__global__ __launch_bounds__(1024) void scan_kernel(const int* __restrict__ cnt,
                                                    int* __restrict__ rowptr) {
    __shared__ int part[1024];
    int t = threadIdx.x;
    const int CHUNK = 40;
    int base = t * CHUNK;
    int s = 0;
    if (t < 1000)
        for (int i = 0; i < CHUNK; ++i) s += cnt[base + i];
    part[t] = s;
    __syncthreads();
    for (int off = 1; off < 1024; off <<= 1) {
        int v = (t >= off) ? part[t - off] : 0;
        __syncthreads();
        part[t] += v;
        __syncthreads();
    }
    int excl = (t == 0) ? 0 : part[t - 1];
    if (t < 1000) {
        int run = excl;
        for (int i = 0; i < CHUNK; ++i) { rowptr[base + i] = run; run += cnt[base + i]; }
        if (t == 999) rowptr[NPTS] = run;
    }
}

// Edge record 16B: {sender | cell<<16, bf16(w00)|bf16(w01)<<16,
//                   bf16(w10)|bf16(w11)<<16, 0}
__global__ void fill_kernel(const float* __restrict__ rel_pos,
                            const int* __restrict__ receivers,
                            const int* __restrict__ senders,
                            const int* __restrict__ ws_ptr,
                            const int* __restrict__ rowptr,
                            int* __restrict__ cursor,
                            uint4* __restrict__ ec) {
    int e = blockIdx.x * blockDim.x + threadIdx.x;
    if (e >= NEDGE) return;
    int cell; float4 w4;
    if (!edge_geom(rel_pos, ws_ptr, e, cell, w4)) return;
    int recv = receivers[e];
    int pos = rowptr[recv] + atomicAdd(&cursor[recv], 1);
    unsigned meta = (unsigned)senders[e] | ((unsigned)cell << 16);
    unsigned wlo = (unsigned)f2bf(w4.x) | ((unsigned)f2bf(w4.y) << 16);
    unsigned whi = (unsigned)f2bf(w4.z) | ((unsigned)f2bf(w4.w) << 16);
    ec[pos] = make_uint4(meta, wlo, whi, 0u);
}

// ===========================================================================
// Merged W repack into bf16 MFMA B-fragment layout.
// ===========================================================================
__global__ void pack_all_kernel(const float* __restrict__ W1, const float* __restrict__ W2,
                                const float* __restrict__ W3, const float* __restrict__ W4,
                                unsigned short* __restrict__ Wp1, unsigned short* __restrict__ Wp2,
                                unsigned short* __restrict__ Wp3, unsigned short* __restrict__ Wp4) {
    int idx = blockIdx.x * 256 + threadIdx.x;
    const float* W; unsigned short* Wp; int M, COUT, base;
    if (idx < 65536)       { W = W1; Wp = Wp1; M = 1024; COUT = 64; base = 0; }
    else if (idx < 98304)  { W = W2; Wp = Wp2; M = 1024; COUT = 32; base = 65536; }
    else if (idx < 131072) { W = W3; Wp = Wp3; M = 512;  COUT = 64; base = 98304; }
    else if (idx < 163840) { W = W4; Wp = Wp4; M = 1024; COUT = 32; base = 131072; }
    else return;
    int i = idx - base;
    int nKS = M / 32;
    int j = i & 7, l = (i >> 3) & 63, t = i >> 9;
    int ks = t % nKS, cb = t / nKS;
    int m = ks * 32 + (l >> 4) * 8 + j;
    int col = cb * 16 + (l & 15);
    Wp[i] = f2bf(W[(size_t)m * COUT + col]);
}

// bf16 concat(x,y) -> xab[N][64]
__global__ void build_xab_kernel(const float* __restrict__ x,
                                 const float* __restrict__ y,
                                 unsigned short* __restrict__ xab) {
    int t = blockIdx.x * blockDim.x + threadIdx.x;
    if (t >= NPTS * 64) return;
    int n = t >> 6, c = t & 63;
    xab[t] = f2bf((c < 32) ? x[n * 32 + c] : y[n * 32 + (c - 32)]);
}

// ===========================================================================
// Fused cconv layer, MFMA scatter + MFMA GEMM.
// Phase 1 (NEW): per wave, 4 receivers sequentially. For each 32-edge chunk:
//  stage records in LDS; A-fragment = cell-corner weight (bit-select from the
//  4 precomputed bf16 corner products; lane's (cx,cy) fixed); B-fragment =
//  8 bf16 feature gathers per colblock; 1 mfma per colblock accumulates
//  S[16 cells][16 ch]. C layout (r16-validated): row=(l>>4)*4+i, col=l&15.
// Phase 2: unchanged MFMA GEMM vs fragment-packed W + fused BN partials.
// ===========================================================================
template <int CIN, int COUT>
__global__ __launch_bounds__(256, 4) void fused_layer(const unsigned short* __restrict__ featb,
                                                      const uint4* __restrict__ ec,
                                                      const int* __restrict__ rowptr,
                                                      const unsigned short* __restrict__ Wp,
                                                      const float* __restrict__ a,
                                                      float* __restrict__ P,
                                                      float* __restrict__ part) {
    constexpr int RB = 16;
    constexpr int M = 16 * CIN;
    constexpr int LDB = M + 8;
    constexpr int nKS = M / 32;
    constexpr int NCB = CIN / 16;     // feature colblocks
    constexpr int CT = COUT / 16;     // output colblocks
    __shared__ short S_bf[RB * LDB];
    __shared__ uint4 stage[4][32];
    __shared__ float Rred[CT == 2 ? 512 : 4];

    int tid = threadIdx.x;
    int lane = tid & 63;
    int wave = tid >> 6;
    int col = lane & 15;
    int kgrp = lane >> 4;
    int rcx = col >> 2, rcy = col & 3;    // this lane's cell (A row)

    for (int r = 0; r < 4; ++r) {
        int rloc = wave * 4 + r;
        int rglob = blockIdx.x * RB + rloc;
        int rs = rowptr[rglob];
        int deg = rowptr[rglob + 1] - rs;

        f32x4 acc[NCB];
#pragma unroll
        for (int cb = 0; cb < NCB; ++cb) acc[cb] = f32x4{0.f, 0.f, 0.f, 0.f};

        for (int c0 = 0; c0 < deg; c0 += 32) {
            if (lane < 32) {
                uint4 rec = (c0 + lane < deg) ? ec[rs + c0 + lane]
                                              : make_uint4(0u, 0u, 0u, 0u);
                stage[wave][lane] = rec;
            }
            // same-wave LDS dependency; compiler inserts lgkmcnt waits
            unsigned aw[8];
            int sb[8];
#pragma unroll
            for (int j = 0; j < 8; ++j) {
                uint4 rec = stage[wave][kgrp * 8 + j];
                int cell = (int)(rec.x >> 16);
                int ix = cell >> 2, iy = cell & 3;
                unsigned pair = (rcx == ix) ? rec.y : rec.z;
                unsigned half = (rcy == iy) ? (pair & 0xFFFFu) : (pair >> 16);
                bool vx = (rcx == ix) || (rcx == ix + 1);
                bool vy = (rcy == iy) || (rcy == iy + 1);
                aw[j] = (vx && vy) ? half : 0u;
                sb[j] = (int)(rec.x & 0xFFFFu) * CIN + col;
            }
            bf16x8 afrag = pack8(aw[0], aw[1], aw[2], aw[3], aw[4], aw[5], aw[6], aw[7]);
#pragma unroll
            for (int cb = 0; cb < NCB; ++cb) {
                unsigned b0 = featb[sb[0] + cb * 16];
                unsigned b1 = featb[sb[1] + cb * 16];
                unsigned b2 = featb[sb[2] + cb * 16];
                unsigned b3 = featb[sb[3] + cb * 16];
                unsigned b4 = featb[sb[4] + cb * 16];
                unsigned b5 = featb[sb[5] + cb * 16];
                unsigned b6 = featb[sb[6] + cb * 16];
                unsigned b7 = featb[sb[7] + cb * 16];
                bf16x8 bfrag = pack8(b0, b1, b2, b3, b4, b5, b6, b7);
                acc[cb] = __builtin_amdgcn_mfma_f32_16x16x32_bf16(afrag, bfrag, acc[cb], 0, 0, 0);
            }
        }

        // epilogue: S_r[cell][ch] -> S_bf row rloc (cell row = kgrp*4+i)
        short* srow = &S_bf[rloc * LDB];
#pragma unroll
        for (int cb = 0; cb < NCB; ++cb)
#pragma unroll
            for (int i = 0; i < 4; ++i)
                srow[(kgrp * 4 + i) * CIN + cb * 16 + col] = (short)f2bf(acc[cb][i]);
    }
    __syncthreads();

    // --- phase 2: MFMA GEMM (unchanged from r20) ---
    int row16 = lane & 15;
    f32x4 c = {0.f, 0.f, 0.f, 0.f};
    int cb, ks0;
    constexpr int KS_PER = (CT == 4) ? nKS : nKS / 2;
    if constexpr (CT == 4) { cb = wave; ks0 = 0; }
    else { cb = wave & 1; ks0 = (wave >> 1) * KS_PER; }

    const short* abase = &S_bf[row16 * LDB + kgrp * 8];
    const bf16x8* wfrag = (const bf16x8*)Wp;
    size_t wbase = (size_t)(cb * nKS + ks0) * 64 + lane;
#pragma unroll 8
    for (int kk = 0; kk < KS_PER; ++kk) {
        bf16x8 af = *(const bf16x8*)(abase + (size_t)(ks0 + kk) * 32);
        bf16x8 bf = wfrag[wbase + (size_t)kk * 64];
        c = __builtin_amdgcn_mfma_f32_16x16x32_bf16(af, bf, c, 0, 0, 0);
    }

    if constexpr (CT == 2) {
        if (wave >= 2) {
#pragma unroll
            for (int i = 0; i < 4; ++i)
                Rred[cb * 256 + (kgrp * 4 + i) * 16 + row16] = c[i];
        }
        __syncthreads();
        if (wave < 2) {
            float sp = 0.f, sq = 0.f;
#pragma unroll
            for (int i = 0; i < 4; ++i) {
                int row = kgrp * 4 + i;
                int n = blockIdx.x * RB + row;
                float v = a[n] * (c[i] + Rred[cb * 256 + row * 16 + row16]);
                P[(size_t)n * COUT + cb * 16 + row16] = v;
                sp += v; sq += v * v;
            }
            sp += __shfl_xor(sp, 16); sp += __shfl_xor(sp, 32);
            sq += __shfl_xor(sq, 16); sq += __shfl_xor(sq, 32);
            if (kgrp == 0) {
                part[(size_t)blockIdx.x * 2 * COUT + cb * 16 + row16] = sp;
                part[(size_t)blockIdx.x * 2 * COUT + COUT + cb * 16 + row16] = sq;
            }
        }
    } else {
        float sp = 0.f, sq = 0.f;
#pragma unroll
        for (int i = 0; i < 4; ++i) {
            int row = kgrp * 4 + i;
            int n = blockIdx.x * RB + row;
            float v = a[n] * c[i];
            P[(size_t)n * COUT + cb * 16 + row16] = v;
            sp += v; sq += v * v;
        }
        sp += __shfl_xor(sp, 16); sp += __shfl_xor(sp, 32);
        sq += __shfl_xor(sq, 16); sq += __shfl_xor(sq, 32);
        if (kgrp == 0) {
            part[(size_t)blockIdx.x * 2 * COUT + cb * 16 + row16] = sp;
            part[(size_t)blockIdx.x * 2 * COUT + COUT + cb * 16 + row16] = sq;
        }
    }
}

// ===========================================================================
// BN reduction (r20, static trip counts).
// ===========================================================================
template <int COUT>
__global__ __launch_bounds__(256) void bn_mid_kernel(const float* __restrict__ part,
                                                     float* __restrict__ part2) {
    constexpr int C2 = 2 * COUT;
    constexpr int NG = 256 / C2;
    constexpr int NB = NPTS / 16;
    constexpr int NRB = (NB + 63) / 64;
    __shared__ float ls[256];
    int tid = threadIdx.x;
    int d = tid % C2;
    int gi = tid / C2;
    int k0 = blockIdx.x * NRB;
    float s = 0.f;
#pragma unroll
    for (int j = 0; j < NRB / NG + 1; ++j) {
        int k = k0 + gi + j * NG;
        bool ok = (gi + j * NG < NRB) && (k < NB);
        s += ok ? part[(size_t)k * C2 + d] : 0.f;
    }
    ls[tid] = s;
    __syncthreads();
    if (gi == 0) {
        float tot = s;
#pragma unroll
        for (int g2 = 1; g2 < NG; ++g2) tot += ls[tid + g2 * C2];
        part2[(size_t)blockIdx.x * C2 + d] = tot;
    }
}

template <int COUT>
__global__ __launch_bounds__(1024) void bn_fin_kernel(const float* __restrict__ part2,
                                                      const float* __restrict__ g,
                                                      const float* __restrict__ b,
                                                      float* __restrict__ scb) {
    constexpr int C2 = 2 * COUT;
    constexpr int NG = 1024 / C2;
    __shared__ float ls[1024];
    int tid = threadIdx.x;
    int d = tid % C2;
    int gi = tid / C2;
    float s = 0.f;
#pragma unroll
    for (int j = 0; j < 64 / NG; ++j)
        s += part2[(size_t)(gi + j * NG) * C2 + d];
    ls[tid] = s;
    __syncthreads();
    if (tid < C2) {
        float tot = ls[tid];
#pragma unroll
        for (int g2 = 1; g2 < NG; ++g2) tot += ls[tid + g2 * C2];
        ls[tid] = tot;
    }
    __syncthreads();
    if (tid < COUT) {
        float sum = ls[tid], ssq = ls[COUT + tid];
        float mean = sum / (float)NPTS;
        float var = ssq / (float)NPTS - mean * mean;
        float inv = rsqrtf(var + BN_EPS);
        float scale = inv * g[tid];
        scb[tid] = scale;
        scb[COUT + tid] = b[tid] - mean * scale;
    }
}

// relu(bn(P)) -> bf16 feature buffer
template <int COUT>
__global__ void apply_relu_bf16_kernel(const float* __restrict__ P,
                                       const float* __restrict__ scb,
                                       unsigned short* __restrict__ fb) {
    int t = blockIdx.x * blockDim.x + threadIdx.x;
    if (t >= NPTS * COUT) return;
    int d = t % COUT;
    float v = P[t] * scb[d] + scb[COUT + d];
    fb[t] = f2bf(fmaxf(v, 0.0f));
}

// sigmoid-mix -> bf16 feature buffer (layer-2 output -> layer-3 input)
__global__ void apply_sigmix_bf16_kernel(const float* __restrict__ P,
                                         const float* __restrict__ scb,
                                         const float* __restrict__ x,
                                         const float* __restrict__ y,
                                         unsigned short* __restrict__ xob) {
    int t = blockIdx.x * blockDim.x + threadIdx.x;
    if (t >= NPTS * 32) return;
    int d = t & 31;
    float v = P[t] * scb[d] + scb[32 + d];
    float w = 1.0f / (1.0f + expf(-v));
    xob[t] = f2bf(2.0f * x[t] * w + 2.0f * y[t] * (1.0f - w));
}

// final sigmoid-mix -> f32 output
__global__ void apply_sigmix_kernel(const float* __restrict__ P,
                                    const float* __restrict__ scb,
                                    const float* __restrict__ x,
                                    const float* __restrict__ y,
                                    float* __restrict__ out) {
    int t = blockIdx.x * blockDim.x + threadIdx.x;
    if (t >= NPTS * 32) return;
    int d = t & 31;
    float v = P[t] * scb[d] + scb[32 + d];
    float w = 1.0f / (1.0f + expf(-v));
    out[t] = 2.0f * x[t] * w + 2.0f * y[t] * (1.0f - w);
}

extern "C" void kernel_launch(void* const* d_in, const int* in_sizes, int n_in,
                              void* d_out, int out_size, void* d_ws, size_t ws_size,
                              hipStream_t stream) {
    const float* x = (const float*)d_in[0];
    const float* y = (const float*)d_in[1];
    const int* senders = (const int*)d_in[2];
    const int* receivers = (const int*)d_in[3];
    const float* rel_pos = (const float*)d_in[4];
    const int* ws_ptr = (const int*)d_in[5];
    const float* a = (const float*)d_in[6];
    const float* W1 = (const float*)d_in[7];
    const float* W2 = (const float*)d_in[8];
    const float* W3 = (const float*)d_in[9];
    const float* W4 = (const float*)d_in[10];
    const float* g1 = (const float*)d_in[11];
    const float* b1 = (const float*)d_in[12];
    const float* g2 = (const float*)d_in[13];
    const float* b2 = (const float*)d_in[14];
    const float* g3 = (const float*)d_in[15];
    const float* b3 = (const float*)d_in[16];
    const float* g4 = (const float*)d_in[17];
    const float* b4 = (const float*)d_in[18];

    char* ws = (char*)d_ws;
    size_t off = 0;
    auto alloc = [&](size_t bytes) -> void* {
        void* p = ws + off;
        off += (bytes + 255) & ~(size_t)255;
        return p;
    };
    int* cnt = (int*)alloc((size_t)NPTS * sizeof(int));
    int* cursor = (int*)alloc((size_t)NPTS * sizeof(int));
    int* rowptr = (int*)alloc((size_t)(NPTS + 1) * sizeof(int));
    uint4* ec = (uint4*)alloc((size_t)(NEDGE + 4) * sizeof(uint4));
    unsigned short* xab = (unsigned short*)alloc((size_t)NPTS * 64 * 2);
    unsigned short* fb64 = (unsigned short*)alloc((size_t)NPTS * 64 * 2);
    unsigned short* xob = (unsigned short*)alloc((size_t)NPTS * 32 * 2);
    float* P1 = (float*)alloc((size_t)NPTS * 64 * sizeof(float));  // also P3
    float* P2 = (float*)alloc((size_t)NPTS * 32 * sizeof(float));  // also P4
    float* part = (float*)alloc((size_t)(NPTS / 16) * 128 * sizeof(float));
    float* part2 = (float*)alloc((size_t)64 * 128 * sizeof(float));
    float* scb = (float*)alloc(2 * 64 * sizeof(float));
    unsigned short* Wp1 = (unsigned short*)alloc((size_t)1024 * 64 * 2);
    unsigned short* Wp2 = (unsigned short*)alloc((size_t)1024 * 32 * 2);
    unsigned short* Wp3 = (unsigned short*)alloc((size_t)512 * 64 * 2);
    unsigned short* Wp4 = (unsigned short*)alloc((size_t)1024 * 32 * 2);
    (void)ws_size; (void)in_sizes; (void)n_in; (void)out_size;

    // --- prologue ---
    pack_all_kernel<<<640, 256, 0, stream>>>(W1, W2, W3, W4, Wp1, Wp2, Wp3, Wp4);
    hipMemsetAsync(cnt, 0, (size_t)2 * NPTS * sizeof(int), stream);  // cnt+cursor
    hist_kernel<<<(NEDGE + 255) / 256, 256, 0, stream>>>(rel_pos, receivers, ws_ptr, cnt);
    scan_kernel<<<1, 1024, 0, stream>>>(cnt, rowptr);
    fill_kernel<<<(NEDGE + 255) / 256, 256, 0, stream>>>(rel_pos, receivers, senders, ws_ptr,
                                                         rowptr, cursor, ec);
    build_xab_kernel<<<(NPTS * 64 + 255) / 256, 256, 0, stream>>>(x, y, xab);

    // Layer 1
    fused_layer<64, 64><<<NPTS / 16, 256, 0, stream>>>(xab, ec, rowptr, Wp1, a, P1, part);
    bn_mid_kernel<64><<<64, 256, 0, stream>>>(part, part2);
    bn_fin_kernel<64><<<1, 1024, 0, stream>>>(part2, g1, b1, scb);
    apply_relu_bf16_kernel<64><<<(NPTS * 64 + 255) / 256, 256, 0, stream>>>(P1, scb, fb64);

    // Layer 2
    fused_layer<64, 32><<<NPTS / 16, 256, 0, stream>>>(fb64, ec, rowptr, Wp2, a, P2, part);
    bn_mid_kernel<32><<<64, 256, 0, stream>>>(part, part2);
    bn_fin_kernel<32><<<1, 1024, 0, stream>>>(part2, g2, b2, scb);
    apply_sigmix_bf16_kernel<<<(NPTS * 32 + 255) / 256, 256, 0, stream>>>(P2, scb, x, y, xob);

    // Layer 3
    fused_layer<32, 64><<<NPTS / 16, 256, 0, stream>>>(xob, ec, rowptr, Wp3, a, P1, part);
    bn_mid_kernel<64><<<64, 256, 0, stream>>>(part, part2);
    bn_fin_kernel<64><<<1, 1024, 0, stream>>>(part2, g3, b3, scb);
    apply_relu_bf16_kernel<64><<<(NPTS * 64 + 255) / 256, 256, 0, stream>>>(P1, scb, fb64);

    // Layer 4
    fused_layer<64, 32><<<NPTS / 16, 256, 0, stream>>>(fb64, ec, rowptr, Wp4, a, P2, part);
    bn_mid_kernel<32><<<64, 256, 0, stream>>>(part, part2);
    bn_fin_kernel<32><<<1, 1024, 0, stream>>>(part2, g4, b4, scb);
    apply_sigmix_kernel<<<(NPTS * 32 + 255) / 256, 256, 0, stream>>>(P2, scb, x, y, (float*)d_out);
}

// Round 22
// 262.592 us; speedup vs baseline: 2.4642x; 1.0112x over previous
//
#include <hip/hip_runtime.h>

#define NPTS 40000
#define NEDGE 1000000
#define BN_EPS 1e-5f

typedef short bf16x8 __attribute__((ext_vector_type(8)));
typedef float f32x4 __attribute__((ext_vector_type(4)));

__device__ __forceinline__ unsigned short f2bf(float x) {
    unsigned u = __float_as_uint(x);
    return (unsigned short)((u + 0x7FFFu + ((u >> 16) & 1u)) >> 16);  // RTN-even
}
__device__ __forceinline__ bf16x8 pack8(unsigned v0, unsigned v1, unsigned v2, unsigned v3,
                                        unsigned v4, unsigned v5, unsigned v6, unsigned v7) {
    uint4 u = make_uint4(v0 | (v1 << 16), v2 | (v3 << 16), v4 | (v5 << 16), v6 | (v7 << 16));
    return __builtin_bit_cast(bf16x8, u);
}

// ===========================================================================
// Edge geometry: validity + cell + corner weights (w00,w01,w10,w11).
// ===========================================================================
__device__ inline bool edge_geom(const float* rel_pos, const int* ws_ptr, int e,
                                 int& cell, float4& w4) {
    float ws = (float)ws_ptr[0];
    float inv_ws = 1.0f / ws;
    float ux = rel_pos[2 * e] * inv_ws;
    float uy = rel_pos[2 * e + 1] * inv_ws;
    float q = 1.0f - (ux * ux + uy * uy);
    if (!(q > 0.0f)) return false;
    float win = q * q * q;
    float gx = fminf(fmaxf((ux + 1.0f) * 1.5f, 0.0f), 3.0f);
    float gy = fminf(fmaxf((uy + 1.0f) * 1.5f, 0.0f), 3.0f);
    int ix = (int)floorf(gx); ix = ix < 0 ? 0 : (ix > 2 ? 2 : ix);
    int iy = (int)floorf(gy); iy = iy < 0 ? 0 : (iy > 2 ? 2 : iy);
    float fx = gx - (float)ix;
    float fy = gy - (float)iy;
    cell = ix * 4 + iy;
    float wx0 = (1.f - fx) * win, wx1 = fx * win;
    float wy0 = 1.f - fy, wy1 = fy;
    w4 = make_float4(wx0 * wy0, wx0 * wy1, wx1 * wy0, wx1 * wy1);
    return true;
}

// 4 edges per thread (independent chains -> atomic/store latency overlaps;
// r21: 1 edge/thread fill was 42us latency-bound at VALUBusy 3.9%)
__global__ void hist_kernel(const float* __restrict__ rel_pos,
                            const int* __restrict__ receivers,
                            const int* __restrict__ ws_ptr,
                            int* __restrict__ cnt) {
    int base = blockIdx.x * 1024 + threadIdx.x;
#pragma unroll
    for (int i = 0; i < 4; ++i) {
        int e = base + i * 256;
        if (e >= NEDGE) continue;
        int cell; float4 w4;
        if (edge_geom(rel_pos, ws_ptr, e, cell, w4))
            atomicAdd(&cnt[receivers[e]], 1);
    }
}

// one block, 1024 threads: exclusive scan of 40000 counts -> rowptr[40001]
__global__ __launch_bounds__(1024) void scan_kernel(const int* __restrict__ cnt,
                                                    int* __restrict__ rowptr) {
    __shared__ int part[1024];
    int t = threadIdx.x;
    const int CHUNK = 40;
    int base = t * CHUNK;
    int s = 0;
    if (t < 1000)
        for (int i = 0; i < CHUNK; ++i) s += cnt[base + i];
    part[t] = s;
    __syncthreads();
    for (int off = 1; off < 1024; off <<= 1) {
        int v = (t >= off) ? part[t - off] : 0;
        __syncthreads();
        part[t] += v;
        __syncthreads();
    }
    int excl = (t == 0) ? 0 : part[t - 1];
    if (t < 1000) {
        int run = excl;
        for (int i = 0; i < CHUNK; ++i) { rowptr[base + i] = run; run += cnt[base + i]; }
        if (t == 999) rowptr[NPTS] = run;
    }
}

// Edge record 16B: {sender | cell<<16, bf16(w00)|bf16(w01)<<16,
//                   bf16(w10)|bf16(w11)<<16, 0}; 4 edges per thread.
__global__ void fill_kernel(const float* __restrict__ rel_pos,
                            const int* __restrict__ receivers,
                            const int* __restrict__ senders,
                            const int* __restrict__ ws_ptr,
                            const int* __restrict__ rowptr,
                            int* __restrict__ cursor,
                            uint4* __restrict__ ec) {
    int base = blockIdx.x * 1024 + threadIdx.x;
#pragma unroll
    for (int i = 0; i < 4; ++i) {
        int e = base + i * 256;
        if (e >= NEDGE) continue;
        int cell; float4 w4;
        if (!edge_geom(rel_pos, ws_ptr, e, cell, w4)) continue;
        int recv = receivers[e];
        int pos = rowptr[recv] + atomicAdd(&cursor[recv], 1);
        unsigned meta = (unsigned)senders[e] | ((unsigned)cell << 16);
        unsigned wlo = (unsigned)f2bf(w4.x) | ((unsigned)f2bf(w4.y) << 16);
        unsigned whi = (unsigned)f2bf(w4.z) | ((unsigned)f2bf(w4.w) << 16);
        ec[pos] = make_uint4(meta, wlo, whi, 0u);
    }
}

// ===========================================================================
// Merged W repack into bf16 MFMA B-fragment layout.
// ===========================================================================
__global__ void pack_all_kernel(const float* __restrict__ W1, const float* __restrict__ W2,
                                const float* __restrict__ W3, const float* __restrict__ W4,
                                unsigned short* __restrict__ Wp1, unsigned short* __restrict__ Wp2,
                                unsigned short* __restrict__ Wp3, unsigned short* __restrict__ Wp4) {
    int idx = blockIdx.x * 256 + threadIdx.x;
    const float* W; unsigned short* Wp; int M, COUT, base;
    if (idx < 65536)       { W = W1; Wp = Wp1; M = 1024; COUT = 64; base = 0; }
    else if (idx < 98304)  { W = W2; Wp = Wp2; M = 1024; COUT = 32; base = 65536; }
    else if (idx < 131072) { W = W3; Wp = Wp3; M = 512;  COUT = 64; base = 98304; }
    else if (idx < 163840) { W = W4; Wp = Wp4; M = 1024; COUT = 32; base = 131072; }
    else return;
    int i = idx - base;
    int nKS = M / 32;
    int j = i & 7, l = (i >> 3) & 63, t = i >> 9;
    int ks = t % nKS, cb = t / nKS;
    int m = ks * 32 + (l >> 4) * 8 + j;
    int col = cb * 16 + (l & 15);
    Wp[i] = f2bf(W[(size_t)m * COUT + col]);
}

// bf16 concat(x,y) -> xab[N][64]
__global__ void build_xab_kernel(const float* __restrict__ x,
                                 const float* __restrict__ y,
                                 unsigned short* __restrict__ xab) {
    int t = blockIdx.x * blockDim.x + threadIdx.x;
    if (t >= NPTS * 64) return;
    int n = t >> 6, c = t & 63;
    xab[t] = f2bf((c < 32) ? x[n * 32 + c] : y[n * 32 + (c - 32)]);
}

// ===========================================================================
// Fused cconv layer, MFMA scatter + MFMA GEMM (r21, unchanged).
// ===========================================================================
template <int CIN, int COUT>
__global__ __launch_bounds__(256, 4) void fused_layer(const unsigned short* __restrict__ featb,
                                                      const uint4* __restrict__ ec,
                                                      const int* __restrict__ rowptr,
                                                      const unsigned short* __restrict__ Wp,
                                                      const float* __restrict__ a,
                                                      float* __restrict__ P,
                                                      float* __restrict__ part) {
    constexpr int RB = 16;
    constexpr int M = 16 * CIN;
    constexpr int LDB = M + 8;
    constexpr int nKS = M / 32;
    constexpr int NCB = CIN / 16;
    constexpr int CT = COUT / 16;
    __shared__ short S_bf[RB * LDB];
    __shared__ uint4 stage[4][32];
    __shared__ float Rred[CT == 2 ? 512 : 4];

    int tid = threadIdx.x;
    int lane = tid & 63;
    int wave = tid >> 6;
    int col = lane & 15;
    int kgrp = lane >> 4;
    int rcx = col >> 2, rcy = col & 3;

    for (int r = 0; r < 4; ++r) {
        int rloc = wave * 4 + r;
        int rglob = blockIdx.x * RB + rloc;
        int rs = rowptr[rglob];
        int deg = rowptr[rglob + 1] - rs;

        f32x4 acc[NCB];
#pragma unroll
        for (int cb = 0; cb < NCB; ++cb) acc[cb] = f32x4{0.f, 0.f, 0.f, 0.f};

        for (int c0 = 0; c0 < deg; c0 += 32) {
            if (lane < 32) {
                uint4 rec = (c0 + lane < deg) ? ec[rs + c0 + lane]
                                              : make_uint4(0u, 0u, 0u, 0u);
                stage[wave][lane] = rec;
            }
            unsigned aw[8];
            int sb[8];
#pragma unroll
            for (int j = 0; j < 8; ++j) {
                uint4 rec = stage[wave][kgrp * 8 + j];
                int cell = (int)(rec.x >> 16);
                int ix = cell >> 2, iy = cell & 3;
                unsigned pair = (rcx == ix) ? rec.y : rec.z;
                unsigned half = (rcy == iy) ? (pair & 0xFFFFu) : (pair >> 16);
                bool vx = (rcx == ix) || (rcx == ix + 1);
                bool vy = (rcy == iy) || (rcy == iy + 1);
                aw[j] = (vx && vy) ? half : 0u;
                sb[j] = (int)(rec.x & 0xFFFFu) * CIN + col;
            }
            bf16x8 afrag = pack8(aw[0], aw[1], aw[2], aw[3], aw[4], aw[5], aw[6], aw[7]);
#pragma unroll
            for (int cb = 0; cb < NCB; ++cb) {
                unsigned b0 = featb[sb[0] + cb * 16];
                unsigned b1 = featb[sb[1] + cb * 16];
                unsigned b2 = featb[sb[2] + cb * 16];
                unsigned b3 = featb[sb[3] + cb * 16];
                unsigned b4 = featb[sb[4] + cb * 16];
                unsigned b5 = featb[sb[5] + cb * 16];
                unsigned b6 = featb[sb[6] + cb * 16];
                unsigned b7 = featb[sb[7] + cb * 16];
                bf16x8 bfrag = pack8(b0, b1, b2, b3, b4, b5, b6, b7);
                acc[cb] = __builtin_amdgcn_mfma_f32_16x16x32_bf16(afrag, bfrag, acc[cb], 0, 0, 0);
            }
        }

        short* srow = &S_bf[rloc * LDB];
#pragma unroll
        for (int cb = 0; cb < NCB; ++cb)
#pragma unroll
            for (int i = 0; i < 4; ++i)
                srow[(kgrp * 4 + i) * CIN + cb * 16 + col] = (short)f2bf(acc[cb][i]);
    }
    __syncthreads();

    // --- phase 2: MFMA GEMM ---
    int row16 = lane & 15;
    f32x4 c = {0.f, 0.f, 0.f, 0.f};
    int cb, ks0;
    constexpr int KS_PER = (CT == 4) ? nKS : nKS / 2;
    if constexpr (CT == 4) { cb = wave; ks0 = 0; }
    else { cb = wave & 1; ks0 = (wave >> 1) * KS_PER; }

    const short* abase = &S_bf[row16 * LDB + kgrp * 8];
    const bf16x8* wfrag = (const bf16x8*)Wp;
    size_t wbase = (size_t)(cb * nKS + ks0) * 64 + lane;
#pragma unroll 8
    for (int kk = 0; kk < KS_PER; ++kk) {
        bf16x8 af = *(const bf16x8*)(abase + (size_t)(ks0 + kk) * 32);
        bf16x8 bf = wfrag[wbase + (size_t)kk * 64];
        c = __builtin_amdgcn_mfma_f32_16x16x32_bf16(af, bf, c, 0, 0, 0);
    }

    if constexpr (CT == 2) {
        if (wave >= 2) {
#pragma unroll
            for (int i = 0; i < 4; ++i)
                Rred[cb * 256 + (kgrp * 4 + i) * 16 + row16] = c[i];
        }
        __syncthreads();
        if (wave < 2) {
            float sp = 0.f, sq = 0.f;
#pragma unroll
            for (int i = 0; i < 4; ++i) {
                int row = kgrp * 4 + i;
                int n = blockIdx.x * RB + row;
                float v = a[n] * (c[i] + Rred[cb * 256 + row * 16 + row16]);
                P[(size_t)n * COUT + cb * 16 + row16] = v;
                sp += v; sq += v * v;
            }
            sp += __shfl_xor(sp, 16); sp += __shfl_xor(sp, 32);
            sq += __shfl_xor(sq, 16); sq += __shfl_xor(sq, 32);
            if (kgrp == 0) {
                part[(size_t)blockIdx.x * 2 * COUT + cb * 16 + row16] = sp;
                part[(size_t)blockIdx.x * 2 * COUT + COUT + cb * 16 + row16] = sq;
            }
        }
    } else {
        float sp = 0.f, sq = 0.f;
#pragma unroll
        for (int i = 0; i < 4; ++i) {
            int row = kgrp * 4 + i;
            int n = blockIdx.x * RB + row;
            float v = a[n] * c[i];
            P[(size_t)n * COUT + cb * 16 + row16] = v;
            sp += v; sq += v * v;
        }
        sp += __shfl_xor(sp, 16); sp += __shfl_xor(sp, 32);
        sq += __shfl_xor(sq, 16); sq += __shfl_xor(sq, 32);
        if (kgrp == 0) {
            part[(size_t)blockIdx.x * 2 * COUT + cb * 16 + row16] = sp;
            part[(size_t)blockIdx.x * 2 * COUT + COUT + cb * 16 + row16] = sq;
        }
    }
}

// ===========================================================================
// BN reduction (static trip counts).
// ===========================================================================
template <int COUT>
__global__ __launch_bounds__(256) void bn_mid_kernel(const float* __restrict__ part,
                                                     float* __restrict__ part2) {
    constexpr int C2 = 2 * COUT;
    constexpr int NG = 256 / C2;
    constexpr int NB = NPTS / 16;
    constexpr int NRB = (NB + 63) / 64;
    __shared__ float ls[256];
    int tid = threadIdx.x;
    int d = tid % C2;
    int gi = tid / C2;
    int k0 = blockIdx.x * NRB;
    float s = 0.f;
#pragma unroll
    for (int j = 0; j < NRB / NG + 1; ++j) {
        int k = k0 + gi + j * NG;
        bool ok = (gi + j * NG < NRB) && (k < NB);
        s += ok ? part[(size_t)k * C2 + d] : 0.f;
    }
    ls[tid] = s;
    __syncthreads();
    if (gi == 0) {
        float tot = s;
#pragma unroll
        for (int g2 = 1; g2 < NG; ++g2) tot += ls[tid + g2 * C2];
        part2[(size_t)blockIdx.x * C2 + d] = tot;
    }
}

template <int COUT>
__global__ __launch_bounds__(1024) void bn_fin_kernel(const float* __restrict__ part2,
                                                      const float* __restrict__ g,
                                                      const float* __restrict__ b,
                                                      float* __restrict__ scb) {
    constexpr int C2 = 2 * COUT;
    constexpr int NG = 1024 / C2;
    __shared__ float ls[1024];
    int tid = threadIdx.x;
    int d = tid % C2;
    int gi = tid / C2;
    float s = 0.f;
#pragma unroll
    for (int j = 0; j < 64 / NG; ++j)
        s += part2[(size_t)(gi + j * NG) * C2 + d];
    ls[tid] = s;
    __syncthreads();
    if (tid < C2) {
        float tot = ls[tid];
#pragma unroll
        for (int g2 = 1; g2 < NG; ++g2) tot += ls[tid + g2 * C2];
        ls[tid] = tot;
    }
    __syncthreads();
    if (tid < COUT) {
        float sum = ls[tid], ssq = ls[COUT + tid];
        float mean = sum / (float)NPTS;
        float var = ssq / (float)NPTS - mean * mean;
        float inv = rsqrtf(var + BN_EPS);
        float scale = inv * g[tid];
        scb[tid] = scale;
        scb[COUT + tid] = b[tid] - mean * scale;
    }
}

// relu(bn(P)) -> bf16 feature buffer
template <int COUT>
__global__ void apply_relu_bf16_kernel(const float* __restrict__ P,
                                       const float* __restrict__ scb,
                                       unsigned short* __restrict__ fb) {
    int t = blockIdx.x * blockDim.x + threadIdx.x;
    if (t >= NPTS * COUT) return;
    int d = t % COUT;
    float v = P[t] * scb[d] + scb[COUT + d];
    fb[t] = f2bf(fmaxf(v, 0.0f));
}

// sigmoid-mix -> bf16 feature buffer
__global__ void apply_sigmix_bf16_kernel(const float* __restrict__ P,
                                         const float* __restrict__ scb,
                                         const float* __restrict__ x,
                                         const float* __restrict__ y,
                                         unsigned short* __restrict__ xob) {
    int t = blockIdx.x * blockDim.x + threadIdx.x;
    if (t >= NPTS * 32) return;
    int d = t & 31;
    float v = P[t] * scb[d] + scb[32 + d];
    float w = 1.0f / (1.0f + expf(-v));
    xob[t] = f2bf(2.0f * x[t] * w + 2.0f * y[t] * (1.0f - w));
}

// final sigmoid-mix -> f32 output
__global__ void apply_sigmix_kernel(const float* __restrict__ P,
                                    const float* __restrict__ scb,
                                    const float* __restrict__ x,
                                    const float* __restrict__ y,
                                    float* __restrict__ out) {
    int t = blockIdx.x * blockDim.x + threadIdx.x;
    if (t >= NPTS * 32) return;
    int d = t & 31;
    float v = P[t] * scb[d] + scb[32 + d];
    float w = 1.0f / (1.0f + expf(-v));
    out[t] = 2.0f * x[t] * w + 2.0f * y[t] * (1.0f - w);
}

extern "C" void kernel_launch(void* const* d_in, const int* in_sizes, int n_in,
                              void* d_out, int out_size, void* d_ws, size_t ws_size,
                              hipStream_t stream) {
    const float* x = (const float*)d_in[0];
    const float* y = (const float*)d_in[1];
    const int* senders = (const int*)d_in[2];
    const int* receivers = (const int*)d_in[3];
    const float* rel_pos = (const float*)d_in[4];
    const int* ws_ptr = (const int*)d_in[5];
    const float* a = (const float*)d_in[6];
    const float* W1 = (const float*)d_in[7];
    const float* W2 = (const float*)d_in[8];
    const float* W3 = (const float*)d_in[9];
    const float* W4 = (const float*)d_in[10];
    const float* g1 = (const float*)d_in[11];
    const float* b1 = (const float*)d_in[12];
    const float* g2 = (const float*)d_in[13];
    const float* b2 = (const float*)d_in[14];
    const float* g3 = (const float*)d_in[15];
    const float* b3 = (const float*)d_in[16];
    const float* g4 = (const float*)d_in[17];
    const float* b4 = (const float*)d_in[18];

    char* ws = (char*)d_ws;
    size_t off = 0;
    auto alloc = [&](size_t bytes) -> void* {
        void* p = ws + off;
        off += (bytes + 255) & ~(size_t)255;
        return p;
    };
    int* cnt = (int*)alloc((size_t)NPTS * sizeof(int));
    int* cursor = (int*)alloc((size_t)NPTS * sizeof(int));
    int* rowptr = (int*)alloc((size_t)(NPTS + 1) * sizeof(int));
    uint4* ec = (uint4*)alloc((size_t)(NEDGE + 4) * sizeof(uint4));
    unsigned short* xab = (unsigned short*)alloc((size_t)NPTS * 64 * 2);
    unsigned short* fb64 = (unsigned short*)alloc((size_t)NPTS * 64 * 2);
    unsigned short* xob = (unsigned short*)alloc((size_t)NPTS * 32 * 2);
    float* P1 = (float*)alloc((size_t)NPTS * 64 * sizeof(float));  // also P3
    float* P2 = (float*)alloc((size_t)NPTS * 32 * sizeof(float));  // also P4
    float* part = (float*)alloc((size_t)(NPTS / 16) * 128 * sizeof(float));
    float* part2 = (float*)alloc((size_t)64 * 128 * sizeof(float));
    float* scb = (float*)alloc(2 * 64 * sizeof(float));
    unsigned short* Wp1 = (unsigned short*)alloc((size_t)1024 * 64 * 2);
    unsigned short* Wp2 = (unsigned short*)alloc((size_t)1024 * 32 * 2);
    unsigned short* Wp3 = (unsigned short*)alloc((size_t)512 * 64 * 2);
    unsigned short* Wp4 = (unsigned short*)alloc((size_t)1024 * 32 * 2);
    (void)ws_size; (void)in_sizes; (void)n_in; (void)out_size;

    // --- prologue ---
    pack_all_kernel<<<640, 256, 0, stream>>>(W1, W2, W3, W4, Wp1, Wp2, Wp3, Wp4);
    hipMemsetAsync(cnt, 0, (size_t)2 * NPTS * sizeof(int), stream);  // cnt+cursor
    hist_kernel<<<(NEDGE + 1023) / 1024, 256, 0, stream>>>(rel_pos, receivers, ws_ptr, cnt);
    scan_kernel<<<1, 1024, 0, stream>>>(cnt, rowptr);
    fill_kernel<<<(NEDGE + 1023) / 1024, 256, 0, stream>>>(rel_pos, receivers, senders, ws_ptr,
                                                           rowptr, cursor, ec);
    build_xab_kernel<<<(NPTS * 64 + 255) / 256, 256, 0, stream>>>(x, y, xab);

    // Layer 1
    fused_layer<64, 64><<<NPTS / 16, 256, 0, stream>>>(xab, ec, rowptr, Wp1, a, P1, part);
    bn_mid_kernel<64><<<64, 256, 0, stream>>>(part, part2);
    bn_fin_kernel<64><<<1, 1024, 0, stream>>>(part2, g1, b1, scb);
    apply_relu_bf16_kernel<64><<<(NPTS * 64 + 255) / 256, 256, 0, stream>>>(P1, scb, fb64);

    // Layer 2
    fused_layer<64, 32><<<NPTS / 16, 256, 0, stream>>>(fb64, ec, rowptr, Wp2, a, P2, part);
    bn_mid_kernel<32><<<64, 256, 0, stream>>>(part, part2);
    bn_fin_kernel<32><<<1, 1024, 0, stream>>>(part2, g2, b2, scb);
    apply_sigmix_bf16_kernel<<<(NPTS * 32 + 255) / 256, 256, 0, stream>>>(P2, scb, x, y, xob);

    // Layer 3
    fused_layer<32, 64><<<NPTS / 16, 256, 0, stream>>>(xob, ec, rowptr, Wp3, a, P1, part);
    bn_mid_kernel<64><<<64, 256, 0, stream>>>(part, part2);
    bn_fin_kernel<64><<<1, 1024, 0, stream>>>(part2, g3, b3, scb);
    apply_relu_bf16_kernel<64><<<(NPTS * 64 + 255) / 256, 256, 0, stream>>>(P1, scb, fb64);

    // Layer 4
    fused_layer<64, 32><<<NPTS / 16, 256, 0, stream>>>(fb64, ec, rowptr, Wp4, a, P2, part);
    bn_mid_kernel<32><<<64, 256, 0, stream>>>(part, part2);
    bn_fin_kernel<32><<<1, 1024, 0, stream>>>(part2, g4, b4, scb);
    apply_sigmix_kernel<<<(NPTS * 32 + 255) / 256, 256, 0, stream>>>(P2, scb, x, y, (float*)d_out);
}

// Round 23
// 255.711 us; speedup vs baseline: 2.5305x; 1.0269x over previous
//
#include <hip/hip_runtime.h>

#define NPTS 40000
#define NEDGE 1000000
#define BN_EPS 1e-5f

typedef short bf16x8 __attribute__((ext_vector_type(8)));
typedef float f32x4 __attribute__((ext_vector_type(4)));

__device__ __forceinline__ unsigned short f2bf(float x) {
    unsigned u = __float_as_uint(x);
    return (unsigned short)((u + 0x7FFFu + ((u >> 16) & 1u)) >> 16);  // RTN-even
}
__device__ __forceinline__ bf16x8 pack8(unsigned v0, unsigned v1, unsigned v2, unsigned v3,
                                        unsigned v4, unsigned v5, unsigned v6, unsigned v7) {
    uint4 u = make_uint4(v0 | (v1 << 16), v2 | (v3 << 16), v4 | (v5 << 16), v6 | (v7 << 16));
    return __builtin_bit_cast(bf16x8, u);
}

// ===========================================================================
// Edge geometry: validity + cell + corner weights (w00,w01,w10,w11).
// ===========================================================================
__device__ inline bool edge_geom(const float* rel_pos, const int* ws_ptr, int e,
                                 int& cell, float4& w4) {
    float ws = (float)ws_ptr[0];
    float inv_ws = 1.0f / ws;
    float ux = rel_pos[2 * e] * inv_ws;
    float uy = rel_pos[2 * e + 1] * inv_ws;
    float q = 1.0f - (ux * ux + uy * uy);
    if (!(q > 0.0f)) return false;
    float win = q * q * q;
    float gx = fminf(fmaxf((ux + 1.0f) * 1.5f, 0.0f), 3.0f);
    float gy = fminf(fmaxf((uy + 1.0f) * 1.5f, 0.0f), 3.0f);
    int ix = (int)floorf(gx); ix = ix < 0 ? 0 : (ix > 2 ? 2 : ix);
    int iy = (int)floorf(gy); iy = iy < 0 ? 0 : (iy > 2 ? 2 : iy);
    float fx = gx - (float)ix;
    float fy = gy - (float)iy;
    cell = ix * 4 + iy;
    float wx0 = (1.f - fx) * win, wx1 = fx * win;
    float wy0 = 1.f - fy, wy1 = fy;
    w4 = make_float4(wx0 * wy0, wx0 * wy1, wx1 * wy0, wx1 * wy1);
    return true;
}

// 4 edges per thread
__global__ void hist_kernel(const float* __restrict__ rel_pos,
                            const int* __restrict__ receivers,
                            const int* __restrict__ ws_ptr,
                            int* __restrict__ cnt) {
    int base = blockIdx.x * 1024 + threadIdx.x;
#pragma unroll
    for (int i = 0; i < 4; ++i) {
        int e = base + i * 256;
        if (e >= NEDGE) continue;
        int cell; float4 w4;
        if (edge_geom(rel_pos, ws_ptr, e, cell, w4))
            atomicAdd(&cnt[receivers[e]], 1);
    }
}

// one block, 1024 threads: exclusive scan of 40000 counts -> rowptr[40001]
__global__ __launch_bounds__(1024) void scan_kernel(const int* __restrict__ cnt,
                                                    int* __restrict__ rowptr) {
    __shared__ int part[1024];
    int t = threadIdx.x;
    const int CHUNK = 40;
    int base = t * CHUNK;
    int s = 0;
    if (t < 1000)
        for (int i = 0; i < CHUNK; ++i) s += cnt[base + i];
    part[t] = s;
    __syncthreads();
    for (int off = 1; off < 1024; off <<= 1) {
        int v = (t >= off) ? part[t - off] : 0;
        __syncthreads();
        part[t] += v;
        __syncthreads();
    }
    int excl = (t == 0) ? 0 : part[t - 1];
    if (t < 1000) {
        int run = excl;
        for (int i = 0; i < CHUNK; ++i) { rowptr[base + i] = run; run += cnt[base + i]; }
        if (t == 999) rowptr[NPTS] = run;
    }
}

// Edge record 16B: {sender | cell<<16, bf16(w00)|bf16(w01)<<16,
//                   bf16(w10)|bf16(w11)<<16, 0}; 4 edges per thread.
__global__ void fill_kernel(const float* __restrict__ rel_pos,
                            const int* __restrict__ receivers,
                            const int* __restrict__ senders,
                            const int* __restrict__ ws_ptr,
                            const int* __restrict__ rowptr,
                            int* __restrict__ cursor,
                            uint4* __restrict__ ec) {
    int base = blockIdx.x * 1024 + threadIdx.x;
#pragma unroll
    for (int i = 0; i < 4; ++i) {
        int e = base + i * 256;
        if (e >= NEDGE) continue;
        int cell; float4 w4;
        if (!edge_geom(rel_pos, ws_ptr, e, cell, w4)) continue;
        int recv = receivers[e];
        int pos = rowptr[recv] + atomicAdd(&cursor[recv], 1);
        unsigned meta = (unsigned)senders[e] | ((unsigned)cell << 16);
        unsigned wlo = (unsigned)f2bf(w4.x) | ((unsigned)f2bf(w4.y) << 16);
        unsigned whi = (unsigned)f2bf(w4.z) | ((unsigned)f2bf(w4.w) << 16);
        ec[pos] = make_uint4(meta, wlo, whi, 0u);
    }
}

// ===========================================================================
// Merged W repack into bf16 MFMA B-fragment layout.
// ===========================================================================
__global__ void pack_all_kernel(const float* __restrict__ W1, const float* __restrict__ W2,
                                const float* __restrict__ W3, const float* __restrict__ W4,
                                unsigned short* __restrict__ Wp1, unsigned short* __restrict__ Wp2,
                                unsigned short* __restrict__ Wp3, unsigned short* __restrict__ Wp4) {
    int idx = blockIdx.x * 256 + threadIdx.x;
    const float* W; unsigned short* Wp; int M, COUT, base;
    if (idx < 65536)       { W = W1; Wp = Wp1; M = 1024; COUT = 64; base = 0; }
    else if (idx < 98304)  { W = W2; Wp = Wp2; M = 1024; COUT = 32; base = 65536; }
    else if (idx < 131072) { W = W3; Wp = Wp3; M = 512;  COUT = 64; base = 98304; }
    else if (idx < 163840) { W = W4; Wp = Wp4; M = 1024; COUT = 32; base = 131072; }
    else return;
    int i = idx - base;
    int nKS = M / 32;
    int j = i & 7, l = (i >> 3) & 63, t = i >> 9;
    int ks = t % nKS, cb = t / nKS;
    int m = ks * 32 + (l >> 4) * 8 + j;
    int col = cb * 16 + (l & 15);
    Wp[i] = f2bf(W[(size_t)m * COUT + col]);
}

// bf16 concat(x,y) -> xab[N][64]
__global__ void build_xab_kernel(const float* __restrict__ x,
                                 const float* __restrict__ y,
                                 unsigned short* __restrict__ xab) {
    int t = blockIdx.x * blockDim.x + threadIdx.x;
    if (t >= NPTS * 64) return;
    int n = t >> 6, c = t & 63;
    xab[t] = f2bf((c < 32) ? x[n * 32 + c] : y[n * 32 + (c - 32)]);
}

// ===========================================================================
// Fused cconv layer, MFMA scatter + MFMA GEMM.
// Phase 1: colblock cb owns PERMUTED channels {col*NCB + cb} -> one NCB-wide
// load per (edge, lane) instead of NCB scattered ushort gathers (r22: phase 1
// was gather-stall-bound, 32x 2B loads/chunk). Epilogue unpermutes when
// writing S_bf by true channel index, so W-pack/phase-2 are untouched.
// ===========================================================================
template <int CIN, int COUT>
__global__ __launch_bounds__(256, 4) void fused_layer(const unsigned short* __restrict__ featb,
                                                      const uint4* __restrict__ ec,
                                                      const int* __restrict__ rowptr,
                                                      const unsigned short* __restrict__ Wp,
                                                      const float* __restrict__ a,
                                                      float* __restrict__ P,
                                                      float* __restrict__ part) {
    constexpr int RB = 16;
    constexpr int M = 16 * CIN;
    constexpr int LDB = M + 8;
    constexpr int nKS = M / 32;
    constexpr int NCB = CIN / 16;     // feature colblocks (4 or 2)
    constexpr int CT = COUT / 16;     // output colblocks
    __shared__ short S_bf[RB * LDB];
    __shared__ uint4 stage[4][32];
    __shared__ float Rred[CT == 2 ? 512 : 4];

    int tid = threadIdx.x;
    int lane = tid & 63;
    int wave = tid >> 6;
    int col = lane & 15;
    int kgrp = lane >> 4;
    int rcx = col >> 2, rcy = col & 3;

    for (int r = 0; r < 4; ++r) {
        int rloc = wave * 4 + r;
        int rglob = blockIdx.x * RB + rloc;
        int rs = rowptr[rglob];
        int deg = rowptr[rglob + 1] - rs;

        f32x4 acc[NCB];
#pragma unroll
        for (int cb = 0; cb < NCB; ++cb) acc[cb] = f32x4{0.f, 0.f, 0.f, 0.f};

        for (int c0 = 0; c0 < deg; c0 += 32) {
            if (lane < 32) {
                uint4 rec = (c0 + lane < deg) ? ec[rs + c0 + lane]
                                              : make_uint4(0u, 0u, 0u, 0u);
                stage[wave][lane] = rec;
            }
            unsigned aw[8];
            uint2 fv4[8];
            unsigned fv2[8];
#pragma unroll
            for (int j = 0; j < 8; ++j) {
                uint4 rec = stage[wave][kgrp * 8 + j];
                int cell = (int)(rec.x >> 16);
                int ix = cell >> 2, iy = cell & 3;
                unsigned pair = (rcx == ix) ? rec.y : rec.z;
                unsigned half = (rcy == iy) ? (pair & 0xFFFFu) : (pair >> 16);
                bool vx = (rcx == ix) || (rcx == ix + 1);
                bool vy = (rcy == iy) || (rcy == iy + 1);
                aw[j] = (vx && vy) ? half : 0u;
                int sb = (int)(rec.x & 0xFFFFu) * CIN + col * NCB;
                if constexpr (NCB == 4)
                    fv4[j] = *(const uint2*)&featb[sb];
                else
                    fv2[j] = *(const unsigned*)&featb[sb];
            }
            bf16x8 afrag = pack8(aw[0], aw[1], aw[2], aw[3], aw[4], aw[5], aw[6], aw[7]);
            if constexpr (NCB == 4) {
                bf16x8 b0 = pack8(fv4[0].x & 0xFFFFu, fv4[1].x & 0xFFFFu, fv4[2].x & 0xFFFFu,
                                  fv4[3].x & 0xFFFFu, fv4[4].x & 0xFFFFu, fv4[5].x & 0xFFFFu,
                                  fv4[6].x & 0xFFFFu, fv4[7].x & 0xFFFFu);
                bf16x8 b1 = pack8(fv4[0].x >> 16, fv4[1].x >> 16, fv4[2].x >> 16, fv4[3].x >> 16,
                                  fv4[4].x >> 16, fv4[5].x >> 16, fv4[6].x >> 16, fv4[7].x >> 16);
                bf16x8 b2 = pack8(fv4[0].y & 0xFFFFu, fv4[1].y & 0xFFFFu, fv4[2].y & 0xFFFFu,
                                  fv4[3].y & 0xFFFFu, fv4[4].y & 0xFFFFu, fv4[5].y & 0xFFFFu,
                                  fv4[6].y & 0xFFFFu, fv4[7].y & 0xFFFFu);
                bf16x8 b3 = pack8(fv4[0].y >> 16, fv4[1].y >> 16, fv4[2].y >> 16, fv4[3].y >> 16,
                                  fv4[4].y >> 16, fv4[5].y >> 16, fv4[6].y >> 16, fv4[7].y >> 16);
                acc[0] = __builtin_amdgcn_mfma_f32_16x16x32_bf16(afrag, b0, acc[0], 0, 0, 0);
                acc[1] = __builtin_amdgcn_mfma_f32_16x16x32_bf16(afrag, b1, acc[1], 0, 0, 0);
                acc[2] = __builtin_amdgcn_mfma_f32_16x16x32_bf16(afrag, b2, acc[2], 0, 0, 0);
                acc[3] = __builtin_amdgcn_mfma_f32_16x16x32_bf16(afrag, b3, acc[3], 0, 0, 0);
            } else {
                bf16x8 b0 = pack8(fv2[0] & 0xFFFFu, fv2[1] & 0xFFFFu, fv2[2] & 0xFFFFu,
                                  fv2[3] & 0xFFFFu, fv2[4] & 0xFFFFu, fv2[5] & 0xFFFFu,
                                  fv2[6] & 0xFFFFu, fv2[7] & 0xFFFFu);
                bf16x8 b1 = pack8(fv2[0] >> 16, fv2[1] >> 16, fv2[2] >> 16, fv2[3] >> 16,
                                  fv2[4] >> 16, fv2[5] >> 16, fv2[6] >> 16, fv2[7] >> 16);
                acc[0] = __builtin_amdgcn_mfma_f32_16x16x32_bf16(afrag, b0, acc[0], 0, 0, 0);
                acc[1] = __builtin_amdgcn_mfma_f32_16x16x32_bf16(afrag, b1, acc[1], 0, 0, 0);
            }
        }

        // epilogue: unpermute -> S_bf[cell][channel], channel = col*NCB + cb
        short* srow = &S_bf[rloc * LDB];
#pragma unroll
        for (int i = 0; i < 4; ++i) {
            if constexpr (NCB == 4) {
                unsigned lo = (unsigned)f2bf(acc[0][i]) | ((unsigned)f2bf(acc[1][i]) << 16);
                unsigned hi = (unsigned)f2bf(acc[2][i]) | ((unsigned)f2bf(acc[3][i]) << 16);
                *(uint2*)&srow[(kgrp * 4 + i) * CIN + col * 4] = make_uint2(lo, hi);
            } else {
                unsigned lo = (unsigned)f2bf(acc[0][i]) | ((unsigned)f2bf(acc[1][i]) << 16);
                *(unsigned*)&srow[(kgrp * 4 + i) * CIN + col * 2] = lo;
            }
        }
    }
    __syncthreads();

    // --- phase 2: MFMA GEMM (unchanged) ---
    int row16 = lane & 15;
    f32x4 c = {0.f, 0.f, 0.f, 0.f};
    int cb, ks0;
    constexpr int KS_PER = (CT == 4) ? nKS : nKS / 2;
    if constexpr (CT == 4) { cb = wave; ks0 = 0; }
    else { cb = wave & 1; ks0 = (wave >> 1) * KS_PER; }

    const short* abase = &S_bf[row16 * LDB + kgrp * 8];
    const bf16x8* wfrag = (const bf16x8*)Wp;
    size_t wbase = (size_t)(cb * nKS + ks0) * 64 + lane;
#pragma unroll 8
    for (int kk = 0; kk < KS_PER; ++kk) {
        bf16x8 af = *(const bf16x8*)(abase + (size_t)(ks0 + kk) * 32);
        bf16x8 bf = wfrag[wbase + (size_t)kk * 64];
        c = __builtin_amdgcn_mfma_f32_16x16x32_bf16(af, bf, c, 0, 0, 0);
    }

    if constexpr (CT == 2) {
        if (wave >= 2) {
#pragma unroll
            for (int i = 0; i < 4; ++i)
                Rred[cb * 256 + (kgrp * 4 + i) * 16 + row16] = c[i];
        }
        __syncthreads();
        if (wave < 2) {
            float sp = 0.f, sq = 0.f;
#pragma unroll
            for (int i = 0; i < 4; ++i) {
                int row = kgrp * 4 + i;
                int n = blockIdx.x * RB + row;
                float v = a[n] * (c[i] + Rred[cb * 256 + row * 16 + row16]);
                P[(size_t)n * COUT + cb * 16 + row16] = v;
                sp += v; sq += v * v;
            }
            sp += __shfl_xor(sp, 16); sp += __shfl_xor(sp, 32);
            sq += __shfl_xor(sq, 16); sq += __shfl_xor(sq, 32);
            if (kgrp == 0) {
                part[(size_t)blockIdx.x * 2 * COUT + cb * 16 + row16] = sp;
                part[(size_t)blockIdx.x * 2 * COUT + COUT + cb * 16 + row16] = sq;
            }
        }
    } else {
        float sp = 0.f, sq = 0.f;
#pragma unroll
        for (int i = 0; i < 4; ++i) {
            int row = kgrp * 4 + i;
            int n = blockIdx.x * RB + row;
            float v = a[n] * c[i];
            P[(size_t)n * COUT + cb * 16 + row16] = v;
            sp += v; sq += v * v;
        }
        sp += __shfl_xor(sp, 16); sp += __shfl_xor(sp, 32);
        sq += __shfl_xor(sq, 16); sq += __shfl_xor(sq, 32);
        if (kgrp == 0) {
            part[(size_t)blockIdx.x * 2 * COUT + cb * 16 + row16] = sp;
            part[(size_t)blockIdx.x * 2 * COUT + COUT + cb * 16 + row16] = sq;
        }
    }
}

// ===========================================================================
// BN reduction (static trip counts).
// ===========================================================================
template <int COUT>
__global__ __launch_bounds__(256) void bn_mid_kernel(const float* __restrict__ part,
                                                     float* __restrict__ part2) {
    constexpr int C2 = 2 * COUT;
    constexpr int NG = 256 / C2;
    constexpr int NB = NPTS / 16;
    constexpr int NRB = (NB + 63) / 64;
    __shared__ float ls[256];
    int tid = threadIdx.x;
    int d = tid % C2;
    int gi = tid / C2;
    int k0 = blockIdx.x * NRB;
    float s = 0.f;
#pragma unroll
    for (int j = 0; j < NRB / NG + 1; ++j) {
        int k = k0 + gi + j * NG;
        bool ok = (gi + j * NG < NRB) && (k < NB);
        s += ok ? part[(size_t)k * C2 + d] : 0.f;
    }
    ls[tid] = s;
    __syncthreads();
    if (gi == 0) {
        float tot = s;
#pragma unroll
        for (int g2 = 1; g2 < NG; ++g2) tot += ls[tid + g2 * C2];
        part2[(size_t)blockIdx.x * C2 + d] = tot;
    }
}

template <int COUT>
__global__ __launch_bounds__(1024) void bn_fin_kernel(const float* __restrict__ part2,
                                                      const float* __restrict__ g,
                                                      const float* __restrict__ b,
                                                      float* __restrict__ scb) {
    constexpr int C2 = 2 * COUT;
    constexpr int NG = 1024 / C2;
    __shared__ float ls[1024];
    int tid = threadIdx.x;
    int d = tid % C2;
    int gi = tid / C2;
    float s = 0.f;
#pragma unroll
    for (int j = 0; j < 64 / NG; ++j)
        s += part2[(size_t)(gi + j * NG) * C2 + d];
    ls[tid] = s;
    __syncthreads();
    if (tid < C2) {
        float tot = ls[tid];
#pragma unroll
        for (int g2 = 1; g2 < NG; ++g2) tot += ls[tid + g2 * C2];
        ls[tid] = tot;
    }
    __syncthreads();
    if (tid < COUT) {
        float sum = ls[tid], ssq = ls[COUT + tid];
        float mean = sum / (float)NPTS;
        float var = ssq / (float)NPTS - mean * mean;
        float inv = rsqrtf(var + BN_EPS);
        float scale = inv * g[tid];
        scb[tid] = scale;
        scb[COUT + tid] = b[tid] - mean * scale;
    }
}

// relu(bn(P)) -> bf16 feature buffer
template <int COUT>
__global__ void apply_relu_bf16_kernel(const float* __restrict__ P,
                                       const float* __restrict__ scb,
                                       unsigned short* __restrict__ fb) {
    int t = blockIdx.x * blockDim.x + threadIdx.x;
    if (t >= NPTS * COUT) return;
    int d = t % COUT;
    float v = P[t] * scb[d] + scb[COUT + d];
    fb[t] = f2bf(fmaxf(v, 0.0f));
}

// sigmoid-mix -> bf16 feature buffer
__global__ void apply_sigmix_bf16_kernel(const float* __restrict__ P,
                                         const float* __restrict__ scb,
                                         const float* __restrict__ x,
                                         const float* __restrict__ y,
                                         unsigned short* __restrict__ xob) {
    int t = blockIdx.x * blockDim.x + threadIdx.x;
    if (t >= NPTS * 32) return;
    int d = t & 31;
    float v = P[t] * scb[d] + scb[32 + d];
    float w = 1.0f / (1.0f + expf(-v));
    xob[t] = f2bf(2.0f * x[t] * w + 2.0f * y[t] * (1.0f - w));
}

// final sigmoid-mix -> f32 output
__global__ void apply_sigmix_kernel(const float* __restrict__ P,
                                    const float* __restrict__ scb,
                                    const float* __restrict__ x,
                                    const float* __restrict__ y,
                                    float* __restrict__ out) {
    int t = blockIdx.x * blockDim.x + threadIdx.x;
    if (t >= NPTS * 32) return;
    int d = t & 31;
    float v = P[t] * scb[d] + scb[32 + d];
    float w = 1.0f / (1.0f + expf(-v));
    out[t] = 2.0f * x[t] * w + 2.0f * y[t] * (1.0f - w);
}

extern "C" void kernel_launch(void* const* d_in, const int* in_sizes, int n_in,
                              void* d_out, int out_size, void* d_ws, size_t ws_size,
                              hipStream_t stream) {
    const float* x = (const float*)d_in[0];
    const float* y = (const float*)d_in[1];
    const int* senders = (const int*)d_in[2];
    const int* receivers = (const int*)d_in[3];
    const float* rel_pos = (const float*)d_in[4];
    const int* ws_ptr = (const int*)d_in[5];
    const float* a = (const float*)d_in[6];
    const float* W1 = (const float*)d_in[7];
    const float* W2 = (const float*)d_in[8];
    const float* W3 = (const float*)d_in[9];
    const float* W4 = (const float*)d_in[10];
    const float* g1 = (const float*)d_in[11];
    const float* b1 = (const float*)d_in[12];
    const float* g2 = (const float*)d_in[13];
    const float* b2 = (const float*)d_in[14];
    const float* g3 = (const float*)d_in[15];
    const float* b3 = (const float*)d_in[16];
    const float* g4 = (const float*)d_in[17];
    const float* b4 = (const float*)d_in[18];

    char* ws = (char*)d_ws;
    size_t off = 0;
    auto alloc = [&](size_t bytes) -> void* {
        void* p = ws + off;
        off += (bytes + 255) & ~(size_t)255;
        return p;
    };
    int* cnt = (int*)alloc((size_t)NPTS * sizeof(int));
    int* cursor = (int*)alloc((size_t)NPTS * sizeof(int));
    int* rowptr = (int*)alloc((size_t)(NPTS + 1) * sizeof(int));
    uint4* ec = (uint4*)alloc((size_t)(NEDGE + 4) * sizeof(uint4));
    unsigned short* xab = (unsigned short*)alloc((size_t)NPTS * 64 * 2);
    unsigned short* fb64 = (unsigned short*)alloc((size_t)NPTS * 64 * 2);
    unsigned short* xob = (unsigned short*)alloc((size_t)NPTS * 32 * 2);
    float* P1 = (float*)alloc((size_t)NPTS * 64 * sizeof(float));  // also P3
    float* P2 = (float*)alloc((size_t)NPTS * 32 * sizeof(float));  // also P4
    float* part = (float*)alloc((size_t)(NPTS / 16) * 128 * sizeof(float));
    float* part2 = (float*)alloc((size_t)64 * 128 * sizeof(float));
    float* scb = (float*)alloc(2 * 64 * sizeof(float));
    unsigned short* Wp1 = (unsigned short*)alloc((size_t)1024 * 64 * 2);
    unsigned short* Wp2 = (unsigned short*)alloc((size_t)1024 * 32 * 2);
    unsigned short* Wp3 = (unsigned short*)alloc((size_t)512 * 64 * 2);
    unsigned short* Wp4 = (unsigned short*)alloc((size_t)1024 * 32 * 2);
    (void)ws_size; (void)in_sizes; (void)n_in; (void)out_size;

    // --- prologue ---
    pack_all_kernel<<<640, 256, 0, stream>>>(W1, W2, W3, W4, Wp1, Wp2, Wp3, Wp4);
    hipMemsetAsync(cnt, 0, (size_t)2 * NPTS * sizeof(int), stream);  // cnt+cursor
    hist_kernel<<<(NEDGE + 1023) / 1024, 256, 0, stream>>>(rel_pos, receivers, ws_ptr, cnt);
    scan_kernel<<<1, 1024, 0, stream>>>(cnt, rowptr);
    fill_kernel<<<(NEDGE + 1023) / 1024, 256, 0, stream>>>(rel_pos, receivers, senders, ws_ptr,
                                                           rowptr, cursor, ec);
    build_xab_kernel<<<(NPTS * 64 + 255) / 256, 256, 0, stream>>>(x, y, xab);

    // Layer 1
    fused_layer<64, 64><<<NPTS / 16, 256, 0, stream>>>(xab, ec, rowptr, Wp1, a, P1, part);
    bn_mid_kernel<64><<<64, 256, 0, stream>>>(part, part2);
    bn_fin_kernel<64><<<1, 1024, 0, stream>>>(part2, g1, b1, scb);
    apply_relu_bf16_kernel<64><<<(NPTS * 64 + 255) / 256, 256, 0, stream>>>(P1, scb, fb64);

    // Layer 2
    fused_layer<64, 32><<<NPTS / 16, 256, 0, stream>>>(fb64, ec, rowptr, Wp2, a, P2, part);
    bn_mid_kernel<32><<<64, 256, 0, stream>>>(part, part2);
    bn_fin_kernel<32><<<1, 1024, 0, stream>>>(part2, g2, b2, scb);
    apply_sigmix_bf16_kernel<<<(NPTS * 32 + 255) / 256, 256, 0, stream>>>(P2, scb, x, y, xob);

    // Layer 3
    fused_layer<32, 64><<<NPTS / 16, 256, 0, stream>>>(xob, ec, rowptr, Wp3, a, P1, part);
    bn_mid_kernel<64><<<64, 256, 0, stream>>>(part, part2);
    bn_fin_kernel<64><<<1, 1024, 0, stream>>>(part2, g3, b3, scb);
    apply_relu_bf16_kernel<64><<<(NPTS * 64 + 255) / 256, 256, 0, stream>>>(P1, scb, fb64);

    // Layer 4
    fused_layer<64, 32><<<NPTS / 16, 256, 0, stream>>>(fb64, ec, rowptr, Wp4, a, P2, part);
    bn_mid_kernel<32><<<64, 256, 0, stream>>>(part, part2);
    bn_fin_kernel<32><<<1, 1024, 0, stream>>>(part2, g4, b4, scb);
    apply_sigmix_kernel<<<(NPTS * 32 + 255) / 256, 256, 0, stream>>>(P2, scb, x, y, (float*)d_out);
}

// Round 24
// 233.466 us; speedup vs baseline: 2.7717x; 1.0953x over previous
//
#include <hip/hip_runtime.h>

#define NPTS 40000
#define NEDGE 1000000
#define BN_EPS 1e-5f

typedef short bf16x8 __attribute__((ext_vector_type(8)));
typedef float f32x4 __attribute__((ext_vector_type(4)));

__device__ __forceinline__ unsigned short f2bf(float x) {
    unsigned u = __float_as_uint(x);
    return (unsigned short)((u + 0x7FFFu + ((u >> 16) & 1u)) >> 16);  // RTN-even
}
__device__ __forceinline__ bf16x8 pack8(unsigned v0, unsigned v1, unsigned v2, unsigned v3,
                                        unsigned v4, unsigned v5, unsigned v6, unsigned v7) {
    uint4 u = make_uint4(v0 | (v1 << 16), v2 | (v3 << 16), v4 | (v5 << 16), v6 | (v7 << 16));
    return __builtin_bit_cast(bf16x8, u);
}

// ===========================================================================
// Edge geometry: validity + cell + corner weights (w00,w01,w10,w11).
// ===========================================================================
__device__ inline bool edge_geom(const float* rel_pos, const int* ws_ptr, int e,
                                 int& cell, float4& w4) {
    float ws = (float)ws_ptr[0];
    float inv_ws = 1.0f / ws;
    float ux = rel_pos[2 * e] * inv_ws;
    float uy = rel_pos[2 * e + 1] * inv_ws;
    float q = 1.0f - (ux * ux + uy * uy);
    if (!(q > 0.0f)) return false;
    float win = q * q * q;
    float gx = fminf(fmaxf((ux + 1.0f) * 1.5f, 0.0f), 3.0f);
    float gy = fminf(fmaxf((uy + 1.0f) * 1.5f, 0.0f), 3.0f);
    int ix = (int)floorf(gx); ix = ix < 0 ? 0 : (ix > 2 ? 2 : ix);
    int iy = (int)floorf(gy); iy = iy < 0 ? 0 : (iy > 2 ? 2 : iy);
    float fx = gx - (float)ix;
    float fy = gy - (float)iy;
    cell = ix * 4 + iy;
    float wx0 = (1.f - fx) * win, wx1 = fx * win;
    float wy0 = 1.f - fy, wy1 = fy;
    w4 = make_float4(wx0 * wy0, wx0 * wy1, wx1 * wy0, wx1 * wy1);
    return true;
}

// hist also captures each edge's rank within its receiver (the atomicAdd
// return value) so fill needs NO atomic (r23: fill pinned at 42us by ~20-way
// same-address atomic serialization; hist already pays that cost).
__global__ void hist_kernel(const float* __restrict__ rel_pos,
                            const int* __restrict__ receivers,
                            const int* __restrict__ ws_ptr,
                            int* __restrict__ cnt,
                            int* __restrict__ rank) {
    int base = blockIdx.x * 1024 + threadIdx.x;
#pragma unroll
    for (int i = 0; i < 4; ++i) {
        int e = base + i * 256;
        if (e >= NEDGE) continue;
        int cell; float4 w4;
        int r = -1;
        if (edge_geom(rel_pos, ws_ptr, e, cell, w4))
            r = atomicAdd(&cnt[receivers[e]], 1);
        rank[e] = r;
    }
}

// one block, 1024 threads: exclusive scan of 40000 counts -> rowptr[40001]
__global__ __launch_bounds__(1024) void scan_kernel(const int* __restrict__ cnt,
                                                    int* __restrict__ rowptr) {
    __shared__ int part[1024];
    int t = threadIdx.x;
    const int CHUNK = 40;
    int base = t * CHUNK;
    int s = 0;
    if (t < 1000)
        for (int i = 0; i < CHUNK; ++i) s += cnt[base + i];
    part[t] = s;
    __syncthreads();
    for (int off = 1; off < 1024; off <<= 1) {
        int v = (t >= off) ? part[t - off] : 0;
        __syncthreads();
        part[t] += v;
        __syncthreads();
    }
    int excl = (t == 0) ? 0 : part[t - 1];
    if (t < 1000) {
        int run = excl;
        for (int i = 0; i < CHUNK; ++i) { rowptr[base + i] = run; run += cnt[base + i]; }
        if (t == 999) rowptr[NPTS] = run;
    }
}

// Edge record 16B: {sender | cell<<16, bf16(w00)|bf16(w01)<<16,
//                   bf16(w10)|bf16(w11)<<16, 0}; atomic-free via rank[].
__global__ void fill_kernel(const float* __restrict__ rel_pos,
                            const int* __restrict__ receivers,
                            const int* __restrict__ senders,
                            const int* __restrict__ ws_ptr,
                            const int* __restrict__ rowptr,
                            const int* __restrict__ rank,
                            uint4* __restrict__ ec) {
    int base = blockIdx.x * 1024 + threadIdx.x;
#pragma unroll
    for (int i = 0; i < 4; ++i) {
        int e = base + i * 256;
        if (e >= NEDGE) continue;
        int r = rank[e];
        if (r < 0) continue;
        int cell; float4 w4;
        edge_geom(rel_pos, ws_ptr, e, cell, w4);   // valid by construction
        int pos = rowptr[receivers[e]] + r;
        unsigned meta = (unsigned)senders[e] | ((unsigned)cell << 16);
        unsigned wlo = (unsigned)f2bf(w4.x) | ((unsigned)f2bf(w4.y) << 16);
        unsigned whi = (unsigned)f2bf(w4.z) | ((unsigned)f2bf(w4.w) << 16);
        ec[pos] = make_uint4(meta, wlo, whi, 0u);
    }
}

// ===========================================================================
// Merged W repack into bf16 MFMA B-fragment layout.
// ===========================================================================
__global__ void pack_all_kernel(const float* __restrict__ W1, const float* __restrict__ W2,
                                const float* __restrict__ W3, const float* __restrict__ W4,
                                unsigned short* __restrict__ Wp1, unsigned short* __restrict__ Wp2,
                                unsigned short* __restrict__ Wp3, unsigned short* __restrict__ Wp4) {
    int idx = blockIdx.x * 256 + threadIdx.x;
    const float* W; unsigned short* Wp; int M, COUT, base;
    if (idx < 65536)       { W = W1; Wp = Wp1; M = 1024; COUT = 64; base = 0; }
    else if (idx < 98304)  { W = W2; Wp = Wp2; M = 1024; COUT = 32; base = 65536; }
    else if (idx < 131072) { W = W3; Wp = Wp3; M = 512;  COUT = 64; base = 98304; }
    else if (idx < 163840) { W = W4; Wp = Wp4; M = 1024; COUT = 32; base = 131072; }
    else return;
    int i = idx - base;
    int nKS = M / 32;
    int j = i & 7, l = (i >> 3) & 63, t = i >> 9;
    int ks = t % nKS, cb = t / nKS;
    int m = ks * 32 + (l >> 4) * 8 + j;
    int col = cb * 16 + (l & 15);
    Wp[i] = f2bf(W[(size_t)m * COUT + col]);
}

// bf16 concat(x,y) -> xab[N][64]
__global__ void build_xab_kernel(const float* __restrict__ x,
                                 const float* __restrict__ y,
                                 unsigned short* __restrict__ xab) {
    int t = blockIdx.x * blockDim.x + threadIdx.x;
    if (t >= NPTS * 64) return;
    int n = t >> 6, c = t & 63;
    xab[t] = f2bf((c < 32) ? x[n * 32 + c] : y[n * 32 + (c - 32)]);
}

// ===========================================================================
// Fused cconv layer, MFMA scatter + MFMA GEMM (r23: permuted colblocks ->
// one NCB-wide feature load per edge per lane).
// ===========================================================================
template <int CIN, int COUT>
__global__ __launch_bounds__(256, 4) void fused_layer(const unsigned short* __restrict__ featb,
                                                      const uint4* __restrict__ ec,
                                                      const int* __restrict__ rowptr,
                                                      const unsigned short* __restrict__ Wp,
                                                      const float* __restrict__ a,
                                                      float* __restrict__ P,
                                                      float* __restrict__ part) {
    constexpr int RB = 16;
    constexpr int M = 16 * CIN;
    constexpr int LDB = M + 8;
    constexpr int nKS = M / 32;
    constexpr int NCB = CIN / 16;
    constexpr int CT = COUT / 16;
    __shared__ short S_bf[RB * LDB];
    __shared__ uint4 stage[4][32];
    __shared__ float Rred[CT == 2 ? 512 : 4];

    int tid = threadIdx.x;
    int lane = tid & 63;
    int wave = tid >> 6;
    int col = lane & 15;
    int kgrp = lane >> 4;
    int rcx = col >> 2, rcy = col & 3;

    for (int r = 0; r < 4; ++r) {
        int rloc = wave * 4 + r;
        int rglob = blockIdx.x * RB + rloc;
        int rs = rowptr[rglob];
        int deg = rowptr[rglob + 1] - rs;

        f32x4 acc[NCB];
#pragma unroll
        for (int cb = 0; cb < NCB; ++cb) acc[cb] = f32x4{0.f, 0.f, 0.f, 0.f};

        for (int c0 = 0; c0 < deg; c0 += 32) {
            if (lane < 32) {
                uint4 rec = (c0 + lane < deg) ? ec[rs + c0 + lane]
                                              : make_uint4(0u, 0u, 0u, 0u);
                stage[wave][lane] = rec;
            }
            unsigned aw[8];
            uint2 fv4[8];
            unsigned fv2[8];
#pragma unroll
            for (int j = 0; j < 8; ++j) {
                uint4 rec = stage[wave][kgrp * 8 + j];
                int cell = (int)(rec.x >> 16);
                int ix = cell >> 2, iy = cell & 3;
                unsigned pair = (rcx == ix) ? rec.y : rec.z;
                unsigned half = (rcy == iy) ? (pair & 0xFFFFu) : (pair >> 16);
                bool vx = (rcx == ix) || (rcx == ix + 1);
                bool vy = (rcy == iy) || (rcy == iy + 1);
                aw[j] = (vx && vy) ? half : 0u;
                int sb = (int)(rec.x & 0xFFFFu) * CIN + col * NCB;
                if constexpr (NCB == 4)
                    fv4[j] = *(const uint2*)&featb[sb];
                else
                    fv2[j] = *(const unsigned*)&featb[sb];
            }
            bf16x8 afrag = pack8(aw[0], aw[1], aw[2], aw[3], aw[4], aw[5], aw[6], aw[7]);
            if constexpr (NCB == 4) {
                bf16x8 b0 = pack8(fv4[0].x & 0xFFFFu, fv4[1].x & 0xFFFFu, fv4[2].x & 0xFFFFu,
                                  fv4[3].x & 0xFFFFu, fv4[4].x & 0xFFFFu, fv4[5].x & 0xFFFFu,
                                  fv4[6].x & 0xFFFFu, fv4[7].x & 0xFFFFu);
                bf16x8 b1 = pack8(fv4[0].x >> 16, fv4[1].x >> 16, fv4[2].x >> 16, fv4[3].x >> 16,
                                  fv4[4].x >> 16, fv4[5].x >> 16, fv4[6].x >> 16, fv4[7].x >> 16);
                bf16x8 b2 = pack8(fv4[0].y & 0xFFFFu, fv4[1].y & 0xFFFFu, fv4[2].y & 0xFFFFu,
                                  fv4[3].y & 0xFFFFu, fv4[4].y & 0xFFFFu, fv4[5].y & 0xFFFFu,
                                  fv4[6].y & 0xFFFFu, fv4[7].y & 0xFFFFu);
                bf16x8 b3 = pack8(fv4[0].y >> 16, fv4[1].y >> 16, fv4[2].y >> 16, fv4[3].y >> 16,
                                  fv4[4].y >> 16, fv4[5].y >> 16, fv4[6].y >> 16, fv4[7].y >> 16);
                acc[0] = __builtin_amdgcn_mfma_f32_16x16x32_bf16(afrag, b0, acc[0], 0, 0, 0);
                acc[1] = __builtin_amdgcn_mfma_f32_16x16x32_bf16(afrag, b1, acc[1], 0, 0, 0);
                acc[2] = __builtin_amdgcn_mfma_f32_16x16x32_bf16(afrag, b2, acc[2], 0, 0, 0);
                acc[3] = __builtin_amdgcn_mfma_f32_16x16x32_bf16(afrag, b3, acc[3], 0, 0, 0);
            } else {
                bf16x8 b0 = pack8(fv2[0] & 0xFFFFu, fv2[1] & 0xFFFFu, fv2[2] & 0xFFFFu,
                                  fv2[3] & 0xFFFFu, fv2[4] & 0xFFFFu, fv2[5] & 0xFFFFu,
                                  fv2[6] & 0xFFFFu, fv2[7] & 0xFFFFu);
                bf16x8 b1 = pack8(fv2[0] >> 16, fv2[1] >> 16, fv2[2] >> 16, fv2[3] >> 16,
                                  fv2[4] >> 16, fv2[5] >> 16, fv2[6] >> 16, fv2[7] >> 16);
                acc[0] = __builtin_amdgcn_mfma_f32_16x16x32_bf16(afrag, b0, acc[0], 0, 0, 0);
                acc[1] = __builtin_amdgcn_mfma_f32_16x16x32_bf16(afrag, b1, acc[1], 0, 0, 0);
            }
        }

        // epilogue: unpermute -> S_bf[cell][channel], channel = col*NCB + cb
        short* srow = &S_bf[rloc * LDB];
#pragma unroll
        for (int i = 0; i < 4; ++i) {
            if constexpr (NCB == 4) {
                unsigned lo = (unsigned)f2bf(acc[0][i]) | ((unsigned)f2bf(acc[1][i]) << 16);
                unsigned hi = (unsigned)f2bf(acc[2][i]) | ((unsigned)f2bf(acc[3][i]) << 16);
                *(uint2*)&srow[(kgrp * 4 + i) * CIN + col * 4] = make_uint2(lo, hi);
            } else {
                unsigned lo = (unsigned)f2bf(acc[0][i]) | ((unsigned)f2bf(acc[1][i]) << 16);
                *(unsigned*)&srow[(kgrp * 4 + i) * CIN + col * 2] = lo;
            }
        }
    }
    __syncthreads();

    // --- phase 2: MFMA GEMM ---
    int row16 = lane & 15;
    f32x4 c = {0.f, 0.f, 0.f, 0.f};
    int cb, ks0;
    constexpr int KS_PER = (CT == 4) ? nKS : nKS / 2;
    if constexpr (CT == 4) { cb = wave; ks0 = 0; }
    else { cb = wave & 1; ks0 = (wave >> 1) * KS_PER; }

    const short* abase = &S_bf[row16 * LDB + kgrp * 8];
    const bf16x8* wfrag = (const bf16x8*)Wp;
    size_t wbase = (size_t)(cb * nKS + ks0) * 64 + lane;
#pragma unroll 8
    for (int kk = 0; kk < KS_PER; ++kk) {
        bf16x8 af = *(const bf16x8*)(abase + (size_t)(ks0 + kk) * 32);
        bf16x8 bf = wfrag[wbase + (size_t)kk * 64];
        c = __builtin_amdgcn_mfma_f32_16x16x32_bf16(af, bf, c, 0, 0, 0);
    }

    if constexpr (CT == 2) {
        if (wave >= 2) {
#pragma unroll
            for (int i = 0; i < 4; ++i)
                Rred[cb * 256 + (kgrp * 4 + i) * 16 + row16] = c[i];
        }
        __syncthreads();
        if (wave < 2) {
            float sp = 0.f, sq = 0.f;
#pragma unroll
            for (int i = 0; i < 4; ++i) {
                int row = kgrp * 4 + i;
                int n = blockIdx.x * RB + row;
                float v = a[n] * (c[i] + Rred[cb * 256 + row * 16 + row16]);
                P[(size_t)n * COUT + cb * 16 + row16] = v;
                sp += v; sq += v * v;
            }
            sp += __shfl_xor(sp, 16); sp += __shfl_xor(sp, 32);
            sq += __shfl_xor(sq, 16); sq += __shfl_xor(sq, 32);
            if (kgrp == 0) {
                part[(size_t)blockIdx.x * 2 * COUT + cb * 16 + row16] = sp;
                part[(size_t)blockIdx.x * 2 * COUT + COUT + cb * 16 + row16] = sq;
            }
        }
    } else {
        float sp = 0.f, sq = 0.f;
#pragma unroll
        for (int i = 0; i < 4; ++i) {
            int row = kgrp * 4 + i;
            int n = blockIdx.x * RB + row;
            float v = a[n] * c[i];
            P[(size_t)n * COUT + cb * 16 + row16] = v;
            sp += v; sq += v * v;
        }
        sp += __shfl_xor(sp, 16); sp += __shfl_xor(sp, 32);
        sq += __shfl_xor(sq, 16); sq += __shfl_xor(sq, 32);
        if (kgrp == 0) {
            part[(size_t)blockIdx.x * 2 * COUT + cb * 16 + row16] = sp;
            part[(size_t)blockIdx.x * 2 * COUT + COUT + cb * 16 + row16] = sq;
        }
    }
}

// ===========================================================================
// BN reduction (static trip counts).
// ===========================================================================
template <int COUT>
__global__ __launch_bounds__(256) void bn_mid_kernel(const float* __restrict__ part,
                                                     float* __restrict__ part2) {
    constexpr int C2 = 2 * COUT;
    constexpr int NG = 256 / C2;
    constexpr int NB = NPTS / 16;
    constexpr int NRB = (NB + 63) / 64;
    __shared__ float ls[256];
    int tid = threadIdx.x;
    int d = tid % C2;
    int gi = tid / C2;
    int k0 = blockIdx.x * NRB;
    float s = 0.f;
#pragma unroll
    for (int j = 0; j < NRB / NG + 1; ++j) {
        int k = k0 + gi + j * NG;
        bool ok = (gi + j * NG < NRB) && (k < NB);
        s += ok ? part[(size_t)k * C2 + d] : 0.f;
    }
    ls[tid] = s;
    __syncthreads();
    if (gi == 0) {
        float tot = s;
#pragma unroll
        for (int g2 = 1; g2 < NG; ++g2) tot += ls[tid + g2 * C2];
        part2[(size_t)blockIdx.x * C2 + d] = tot;
    }
}

template <int COUT>
__global__ __launch_bounds__(1024) void bn_fin_kernel(const float* __restrict__ part2,
                                                      const float* __restrict__ g,
                                                      const float* __restrict__ b,
                                                      float* __restrict__ scb) {
    constexpr int C2 = 2 * COUT;
    constexpr int NG = 1024 / C2;
    __shared__ float ls[1024];
    int tid = threadIdx.x;
    int d = tid % C2;
    int gi = tid / C2;
    float s = 0.f;
#pragma unroll
    for (int j = 0; j < 64 / NG; ++j)
        s += part2[(size_t)(gi + j * NG) * C2 + d];
    ls[tid] = s;
    __syncthreads();
    if (tid < C2) {
        float tot = ls[tid];
#pragma unroll
        for (int g2 = 1; g2 < NG; ++g2) tot += ls[tid + g2 * C2];
        ls[tid] = tot;
    }
    __syncthreads();
    if (tid < COUT) {
        float sum = ls[tid], ssq = ls[COUT + tid];
        float mean = sum / (float)NPTS;
        float var = ssq / (float)NPTS - mean * mean;
        float inv = rsqrtf(var + BN_EPS);
        float scale = inv * g[tid];
        scb[tid] = scale;
        scb[COUT + tid] = b[tid] - mean * scale;
    }
}

// relu(bn(P)) -> bf16 feature buffer
template <int COUT>
__global__ void apply_relu_bf16_kernel(const float* __restrict__ P,
                                       const float* __restrict__ scb,
                                       unsigned short* __restrict__ fb) {
    int t = blockIdx.x * blockDim.x + threadIdx.x;
    if (t >= NPTS * COUT) return;
    int d = t % COUT;
    float v = P[t] * scb[d] + scb[COUT + d];
    fb[t] = f2bf(fmaxf(v, 0.0f));
}

// sigmoid-mix -> bf16 feature buffer
__global__ void apply_sigmix_bf16_kernel(const float* __restrict__ P,
                                         const float* __restrict__ scb,
                                         const float* __restrict__ x,
                                         const float* __restrict__ y,
                                         unsigned short* __restrict__ xob) {
    int t = blockIdx.x * blockDim.x + threadIdx.x;
    if (t >= NPTS * 32) return;
    int d = t & 31;
    float v = P[t] * scb[d] + scb[32 + d];
    float w = 1.0f / (1.0f + expf(-v));
    xob[t] = f2bf(2.0f * x[t] * w + 2.0f * y[t] * (1.0f - w));
}

// final sigmoid-mix -> f32 output
__global__ void apply_sigmix_kernel(const float* __restrict__ P,
                                    const float* __restrict__ scb,
                                    const float* __restrict__ x,
                                    const float* __restrict__ y,
                                    float* __restrict__ out) {
    int t = blockIdx.x * blockDim.x + threadIdx.x;
    if (t >= NPTS * 32) return;
    int d = t & 31;
    float v = P[t] * scb[d] + scb[32 + d];
    float w = 1.0f / (1.0f + expf(-v));
    out[t] = 2.0f * x[t] * w + 2.0f * y[t] * (1.0f - w);
}

extern "C" void kernel_launch(void* const* d_in, const int* in_sizes, int n_in,
                              void* d_out, int out_size, void* d_ws, size_t ws_size,
                              hipStream_t stream) {
    const float* x = (const float*)d_in[0];
    const float* y = (const float*)d_in[1];
    const int* senders = (const int*)d_in[2];
    const int* receivers = (const int*)d_in[3];
    const float* rel_pos = (const float*)d_in[4];
    const int* ws_ptr = (const int*)d_in[5];
    const float* a = (const float*)d_in[6];
    const float* W1 = (const float*)d_in[7];
    const float* W2 = (const float*)d_in[8];
    const float* W3 = (const float*)d_in[9];
    const float* W4 = (const float*)d_in[10];
    const float* g1 = (const float*)d_in[11];
    const float* b1 = (const float*)d_in[12];
    const float* g2 = (const float*)d_in[13];
    const float* b2 = (const float*)d_in[14];
    const float* g3 = (const float*)d_in[15];
    const float* b3 = (const float*)d_in[16];
    const float* g4 = (const float*)d_in[17];
    const float* b4 = (const float*)d_in[18];

    char* ws = (char*)d_ws;
    size_t off = 0;
    auto alloc = [&](size_t bytes) -> void* {
        void* p = ws + off;
        off += (bytes + 255) & ~(size_t)255;
        return p;
    };
    int* cnt = (int*)alloc((size_t)NPTS * sizeof(int));
    int* rowptr = (int*)alloc((size_t)(NPTS + 1) * sizeof(int));
    int* rank = (int*)alloc((size_t)NEDGE * sizeof(int));
    uint4* ec = (uint4*)alloc((size_t)(NEDGE + 4) * sizeof(uint4));
    unsigned short* xab = (unsigned short*)alloc((size_t)NPTS * 64 * 2);
    unsigned short* fb64 = (unsigned short*)alloc((size_t)NPTS * 64 * 2);
    unsigned short* xob = (unsigned short*)alloc((size_t)NPTS * 32 * 2);
    float* P1 = (float*)alloc((size_t)NPTS * 64 * sizeof(float));  // also P3
    float* P2 = (float*)alloc((size_t)NPTS * 32 * sizeof(float));  // also P4
    float* part = (float*)alloc((size_t)(NPTS / 16) * 128 * sizeof(float));
    float* part2 = (float*)alloc((size_t)64 * 128 * sizeof(float));
    float* scb = (float*)alloc(2 * 64 * sizeof(float));
    unsigned short* Wp1 = (unsigned short*)alloc((size_t)1024 * 64 * 2);
    unsigned short* Wp2 = (unsigned short*)alloc((size_t)1024 * 32 * 2);
    unsigned short* Wp3 = (unsigned short*)alloc((size_t)512 * 64 * 2);
    unsigned short* Wp4 = (unsigned short*)alloc((size_t)1024 * 32 * 2);
    (void)ws_size; (void)in_sizes; (void)n_in; (void)out_size;

    // --- prologue ---
    pack_all_kernel<<<640, 256, 0, stream>>>(W1, W2, W3, W4, Wp1, Wp2, Wp3, Wp4);
    hipMemsetAsync(cnt, 0, (size_t)NPTS * sizeof(int), stream);
    hist_kernel<<<(NEDGE + 1023) / 1024, 256, 0, stream>>>(rel_pos, receivers, ws_ptr, cnt, rank);
    scan_kernel<<<1, 1024, 0, stream>>>(cnt, rowptr);
    fill_kernel<<<(NEDGE + 1023) / 1024, 256, 0, stream>>>(rel_pos, receivers, senders, ws_ptr,
                                                           rowptr, rank, ec);
    build_xab_kernel<<<(NPTS * 64 + 255) / 256, 256, 0, stream>>>(x, y, xab);

    // Layer 1
    fused_layer<64, 64><<<NPTS / 16, 256, 0, stream>>>(xab, ec, rowptr, Wp1, a, P1, part);
    bn_mid_kernel<64><<<64, 256, 0, stream>>>(part, part2);
    bn_fin_kernel<64><<<1, 1024, 0, stream>>>(part2, g1, b1, scb);
    apply_relu_bf16_kernel<64><<<(NPTS * 64 + 255) / 256, 256, 0, stream>>>(P1, scb, fb64);

    // Layer 2
    fused_layer<64, 32><<<NPTS / 16, 256, 0, stream>>>(fb64, ec, rowptr, Wp2, a, P2, part);
    bn_mid_kernel<32><<<64, 256, 0, stream>>>(part, part2);
    bn_fin_kernel<32><<<1, 1024, 0, stream>>>(part2, g2, b2, scb);
    apply_sigmix_bf16_kernel<<<(NPTS * 32 + 255) / 256, 256, 0, stream>>>(P2, scb, x, y, xob);

    // Layer 3
    fused_layer<32, 64><<<NPTS / 16, 256, 0, stream>>>(xob, ec, rowptr, Wp3, a, P1, part);
    bn_mid_kernel<64><<<64, 256, 0, stream>>>(part, part2);
    bn_fin_kernel<64><<<1, 1024, 0, stream>>>(part2, g3, b3, scb);
    apply_relu_bf16_kernel<64><<<(NPTS * 64 + 255) / 256, 256, 0, stream>>>(P1, scb, fb64);

    // Layer 4
    fused_layer<64, 32><<<NPTS / 16, 256, 0, stream>>>(fb64, ec, rowptr, Wp4, a, P2, part);
    bn_mid_kernel<32><<<64, 256, 0, stream>>>(part, part2);
    bn_fin_kernel<32><<<1, 1024, 0, stream>>>(part2, g4, b4, scb);
    apply_sigmix_kernel<<<(NPTS * 32 + 255) / 256, 256, 0, stream>>>(P2, scb, x, y, (float*)d_out);
}